// Round 5
// baseline (203.630 us; speedup 1.0000x reference)
//
#include <hip/hip_runtime.h>
#include <cmath>

typedef __attribute__((ext_vector_type(4))) float f32x4;
typedef __attribute__((ext_vector_type(8))) short bf16x8;
typedef __attribute__((ext_vector_type(8))) unsigned short u16x8;

#define TSEQ 4096
#define NB 2
#define HID 2048
#define DD 64
#define NH 4
#define NROW 8192
#define SCALE 0.125f
#define NEG_HUGE -3.3e38f

__device__ __forceinline__ float sanef(float v) {
    return fminf(fmaxf(v, -3.3e38f), 3.3e38f);   // NaN->-3.3e38, +/-inf clamped
}
__device__ __forceinline__ float sigm(float z) {
    return 1.0f / (1.0f + __expf(-z));
}
__device__ __forceinline__ unsigned short f2bf(float f) {  // RNE fp32->bf16
    unsigned int u = __float_as_uint(f);
    unsigned int r = u + 0x7FFF + ((u >> 16) & 1);
    return (unsigned short)(r >> 16);
}
__device__ __forceinline__ void gload16(const unsigned short* g, unsigned short* l) {
    __builtin_amdgcn_global_load_lds(
        (const __attribute__((address_space(1))) void*)g,
        (__attribute__((address_space(3))) void*)l, 16, 0, 0);
}

// ============ Kernel 1a: x fp32 -> bf16 (96 MB traffic, HBM-bound) ============
__global__ __launch_bounds__(256)
void cvt_x(const float* __restrict__ x, unsigned short* __restrict__ xb)
{
    const size_t t = (size_t)blockIdx.x * 256 + threadIdx.x;
    #pragma unroll
    for (int i = 0; i < 4; ++i) {
        const size_t base = t * 32 + (size_t)i * 8;
        const float4 a = *(const float4*)(x + base);
        const float4 b = *(const float4*)(x + base + 4);
        u16x8 o;
        o[0] = f2bf(a.x); o[1] = f2bf(a.y); o[2] = f2bf(a.z); o[3] = f2bf(a.w);
        o[4] = f2bf(b.x); o[5] = f2bf(b.y); o[6] = f2bf(b.z); o[7] = f2bf(b.w);
        *(u16x8*)(xb + base) = o;
    }
}

// ============ Kernel 1b: weight concat [384][2048] bf16 (324 real + 60 zero) ============
__global__ __launch_bounds__(256)
void cvt_w(const float* __restrict__ Wq, const float* __restrict__ Wk,
           const float* __restrict__ Ww, unsigned short* __restrict__ Wc)
{
    const int r = blockIdx.x;
    const int c0 = threadIdx.x * 8;
    const float* src = nullptr;
    if (r < 256)      src = Wq + (size_t)r * HID;
    else if (r < 320) src = Wk + (size_t)(r - 256) * HID;
    else if (r < 324) src = Ww + (size_t)(r - 320) * HID;
    u16x8 o = {0, 0, 0, 0, 0, 0, 0, 0};
    if (src) {
        const float4 a = *(const float4*)(src + c0);
        const float4 b = *(const float4*)(src + c0 + 4);
        o[0] = f2bf(a.x); o[1] = f2bf(a.y); o[2] = f2bf(a.z); o[3] = f2bf(a.w);
        o[4] = f2bf(b.x); o[5] = f2bf(b.y); o[6] = f2bf(b.z); o[7] = f2bf(b.w);
    }
    *(u16x8*)(Wc + (size_t)r * HID + c0) = o;
}

// ============ Kernel 2: MFMA projection GEMM (global_load_lds staging) ============
__global__ __launch_bounds__(256)
void proj_mfma(const unsigned short* __restrict__ Xb,
               const unsigned short* __restrict__ Wc,
               const float* __restrict__ bw,
               unsigned short* __restrict__ Qo,
               unsigned short* __restrict__ Ko,
               float* __restrict__ Wo)
{
    __shared__ unsigned short As[128 * 64];
    __shared__ unsigned short Bs[128 * 64];
    const int tid  = threadIdx.x;
    const int row0 = blockIdx.x * 128;
    const int col0 = blockIdx.y * 128;
    const int lane = tid & 63, wid = tid >> 6;
    const int wr = wid >> 1, wc = wid & 1;
    const int sr = tid >> 3, sc = (tid & 7) * 8;     // staging row/col
    const int fr = lane & 15, fk = (lane >> 4) * 8;  // fragment row / k-offset

    f32x4 acc[4][4];
    #pragma unroll
    for (int i = 0; i < 4; ++i)
        #pragma unroll
        for (int j = 0; j < 4; ++j) acc[i][j] = (f32x4){0.f, 0.f, 0.f, 0.f};

    const unsigned short* Ag = Xb + (size_t)(row0 + sr) * HID + sc;
    const unsigned short* Bg = Wc + (size_t)(col0 + sr) * HID + sc;

    for (int kt = 0; kt < HID; kt += 64) {
        __syncthreads();
        // LDS dest per wave: byte off = wid*1024 + c2*4096 + lane*16 (HW adds lane*16)
        #pragma unroll
        for (int c2 = 0; c2 < 4; ++c2) {
            gload16(Ag + (size_t)c2 * 32 * HID + kt, &As[wid * 512 + c2 * 2048]);
            gload16(Bg + (size_t)c2 * 32 * HID + kt, &Bs[wid * 512 + c2 * 2048]);
        }
        __syncthreads();
        #pragma unroll
        for (int kk = 0; kk < 2; ++kk) {
            bf16x8 af[4], bfv[4];
            #pragma unroll
            for (int mi = 0; mi < 4; ++mi)
                af[mi] = *(const bf16x8*)&As[(wr * 64 + mi * 16 + fr) * 64 + kk * 32 + fk];
            #pragma unroll
            for (int ni = 0; ni < 4; ++ni)
                bfv[ni] = *(const bf16x8*)&Bs[(wc * 64 + ni * 16 + fr) * 64 + kk * 32 + fk];
            #pragma unroll
            for (int mi = 0; mi < 4; ++mi)
                #pragma unroll
                for (int ni = 0; ni < 4; ++ni)
                    acc[mi][ni] = __builtin_amdgcn_mfma_f32_16x16x32_bf16(
                        af[mi], bfv[ni], acc[mi][ni], 0, 0, 0);
        }
    }

    const int orow = (lane >> 4) * 4, ocol = lane & 15;
    #pragma unroll
    for (int mi = 0; mi < 4; ++mi) {
        #pragma unroll
        for (int ni = 0; ni < 4; ++ni) {
            const int cg = col0 + wc * 64 + ni * 16 + ocol;
            #pragma unroll
            for (int j = 0; j < 4; ++j) {
                const int rg = row0 + wr * 64 + mi * 16 + orow + j;
                const float v = acc[mi][ni][j];
                if (cg < 256)       Qo[(size_t)rg * 256 + cg] = f2bf(sanef(v));
                else if (cg < 320)  Ko[(size_t)rg * 64 + (cg - 256)] = f2bf(sanef(v));
                else if (cg < 324)  Wo[(size_t)rg * 4 + (cg - 320)] = sanef(sigm(v + bw[cg - 320]));
            }
        }
    }
}

// ============ Kernel 3: gated causal scores — fragment loads direct from L2 ============
// 128x128 tile, 8 waves (2x4), wave tile 64x32. No Q/K LDS (no reuse, L2-resident).
// XCD-bijective remap: 2048 blocks, XCD k owns 256 consecutive work items (Q L2 reuse).
__global__ __launch_bounds__(512)
void score_mfma(const unsigned short* __restrict__ Qb,   // [8192][256]
                const unsigned short* __restrict__ Kb,   // [8192][64]
                const float* __restrict__ Wo,            // [8192][4] = sigmoid(w)
                const float* __restrict__ ib,
                float* __restrict__ out)
{
    const int i0 = blockIdx.z * 1024 + blockIdx.y * 32 + blockIdx.x;
    const int L  = (i0 & 7) * 256 + (i0 >> 3);          // bijective: 2048 % 8 == 0
    const int b  = L >> 10;
    const int it = (L & 1023) >> 5;
    const int jt = L & 31;
    const int tid = threadIdx.x;
    const size_t obase = ((size_t)b * TSEQ + (size_t)it * 128) * TSEQ + (size_t)jt * 128;

    if (jt > it) {  // fully-masked tile: streaming fill
        const int r = tid >> 2, c4 = tid & 3;
        float4* po = (float4*)(out + obase + (size_t)r * TSEQ) + c4 * 8;
        const float4 nh = make_float4(NEG_HUGE, NEG_HUGE, NEG_HUGE, NEG_HUGE);
        #pragma unroll
        for (int i = 0; i < 8; ++i) po[i] = nh;
        return;
    }

    __shared__ float wst[512];                           // [128 rows][4 heads]
    wst[tid & 511] = Wo[((size_t)b * TSEQ + (size_t)it * 128) * 4 + (tid & 511)];
    __syncthreads();

    const int lane = tid & 63, wid = tid >> 6;
    const int wr = wid >> 2, wc = wid & 3;               // wave tile (wr*64, wc*32)
    const int fr = lane & 15, fk8 = (lane >> 4) * 8;

    const unsigned short* Qp = Qb + ((size_t)(b * TSEQ + it * 128 + wr * 64 + fr)) * 256 + fk8;
    const unsigned short* Kp = Kb + ((size_t)(b * TSEQ + jt * 128 + wc * 32 + fr)) * 64 + fk8;
    const float4 ibv = *(const float4*)ib;

    f32x4 fin[4][2];
    #pragma unroll
    for (int i = 0; i < 4; ++i)
        #pragma unroll
        for (int j = 0; j < 2; ++j) fin[i][j] = (f32x4){0.f, 0.f, 0.f, 0.f};

    #pragma unroll
    for (int h = 0; h < NH; ++h) {
        f32x4 acc[4][2];
        #pragma unroll
        for (int i = 0; i < 4; ++i)
            #pragma unroll
            for (int j = 0; j < 2; ++j) acc[i][j] = (f32x4){0.f, 0.f, 0.f, 0.f};

        #pragma unroll
        for (int kk = 0; kk < 2; ++kk) {
            bf16x8 qf[4], kf[2];
            #pragma unroll
            for (int mi = 0; mi < 4; ++mi)
                qf[mi] = *(const bf16x8*)(Qp + (size_t)mi * 16 * 256 + h * 64 + kk * 32);
            #pragma unroll
            for (int ni = 0; ni < 2; ++ni)
                kf[ni] = *(const bf16x8*)(Kp + (size_t)ni * 16 * 64 + kk * 32);
            #pragma unroll
            for (int mi = 0; mi < 4; ++mi)
                #pragma unroll
                for (int ni = 0; ni < 2; ++ni)
                    acc[mi][ni] = __builtin_amdgcn_mfma_f32_16x16x32_bf16(
                        qf[mi], kf[ni], acc[mi][ni], 0, 0, 0);
        }

        const float ibh = (h == 0) ? ibv.x : (h == 1) ? ibv.y : (h == 2) ? ibv.z : ibv.w;
        #pragma unroll
        for (int mi = 0; mi < 4; ++mi) {
            #pragma unroll
            for (int j = 0; j < 4; ++j) {
                const int rloc = wr * 64 + mi * 16 + (lane >> 4) * 4 + j;
                const float wsv = wst[rloc * 4 + h];
                #pragma unroll
                for (int ni = 0; ni < 2; ++ni)
                    fin[mi][ni][j] += sigm(acc[mi][ni][j] * SCALE + ibh) * wsv;
            }
        }
    }

    const bool diag = (it == jt);
    #pragma unroll
    for (int mi = 0; mi < 4; ++mi) {
        #pragma unroll
        for (int j = 0; j < 4; ++j) {
            const int rloc = wr * 64 + mi * 16 + (lane >> 4) * 4 + j;
            #pragma unroll
            for (int ni = 0; ni < 2; ++ni) {
                const int cloc = wc * 32 + ni * 16 + fr;
                float v = sanef(fin[mi][ni][j]);
                if (diag && cloc > rloc) v = NEG_HUGE;
                out[obase + (size_t)rloc * TSEQ + cloc] = v;
            }
        }
    }
}

extern "C" void kernel_launch(void* const* d_in, const int* in_sizes, int n_in,
                              void* d_out, int out_size, void* d_ws, size_t ws_size,
                              hipStream_t stream)
{
    const float* x  = (const float*)d_in[0];
    const float* Wq = (const float*)d_in[1];
    const float* Wk = (const float*)d_in[2];
    const float* Ww = (const float*)d_in[3];
    const float* bw = (const float*)d_in[4];
    const float* ib = (const float*)d_in[5];
    float* out = (float*)d_out;

    unsigned short* Xb = (unsigned short*)d_ws;          // 32 MB
    unsigned short* Wc = Xb + (size_t)NROW * HID;        // 1.5 MB
    unsigned short* Qo = Wc + (size_t)384 * HID;         // 4 MB
    unsigned short* Ko = Qo + (size_t)NROW * 256;        // 1 MB
    float*          Wo = (float*)(Ko + (size_t)NROW * 64); // 128 KB

    cvt_x<<<dim3(2048), dim3(256), 0, stream>>>(x, Xb);
    cvt_w<<<dim3(384), dim3(256), 0, stream>>>(Wq, Wk, Ww, Wc);
    proj_mfma<<<dim3(NROW / 128, 3), dim3(256), 0, stream>>>(Xb, Wc, bw, Qo, Ko, Wo);
    score_mfma<<<dim3(TSEQ / 128, TSEQ / 128, NB), dim3(512), 0, stream>>>(
        Qo, Ko, Wo, ib, out);
}

// Round 6
// 145.536 us; speedup vs baseline: 1.3992x; 1.3992x over previous
//
#include <hip/hip_runtime.h>
#include <cmath>

typedef __attribute__((ext_vector_type(4))) float f32x4;
typedef __attribute__((ext_vector_type(8))) short bf16x8;
typedef __attribute__((ext_vector_type(8))) unsigned short u16x8;

#define TSEQ 4096
#define NB 2
#define HID 2048
#define DD 64
#define NH 4
#define NROW 8192
#define SCALE 0.125f
#define NEG_HUGE -3.3e38f
#define NLOG2E 1.4426950408889634f

__device__ __forceinline__ float sanef(float v) {
    return fminf(fmaxf(v, -3.3e38f), 3.3e38f);   // NaN->-3.3e38, +/-inf clamped
}
__device__ __forceinline__ unsigned short f2bf(float f) {  // RNE fp32->bf16
    unsigned int u = __float_as_uint(f);
    unsigned int r = u + 0x7FFF + ((u >> 16) & 1);
    return (unsigned short)(r >> 16);
}
__device__ __forceinline__ float sigm(float z) {
    return 1.0f / (1.0f + __expf(-z));
}
__device__ __forceinline__ void gload16(const unsigned short* g, unsigned short* l) {
    __builtin_amdgcn_global_load_lds(
        (const __attribute__((address_space(1))) void*)g,
        (__attribute__((address_space(3))) void*)l, 16, 0, 0);
}

// ============ Kernel 1a: x fp32 -> bf16 ============
__global__ __launch_bounds__(256)
void cvt_x(const float* __restrict__ x, unsigned short* __restrict__ xb)
{
    const size_t t = (size_t)blockIdx.x * 256 + threadIdx.x;
    #pragma unroll
    for (int i = 0; i < 4; ++i) {
        const size_t base = t * 32 + (size_t)i * 8;
        const float4 a = *(const float4*)(x + base);
        const float4 b = *(const float4*)(x + base + 4);
        u16x8 o;
        o[0] = f2bf(a.x); o[1] = f2bf(a.y); o[2] = f2bf(a.z); o[3] = f2bf(a.w);
        o[4] = f2bf(b.x); o[5] = f2bf(b.y); o[6] = f2bf(b.z); o[7] = f2bf(b.w);
        *(u16x8*)(xb + base) = o;
    }
}

// ============ Kernel 1b: weight concat [384][2048] bf16 ============
__global__ __launch_bounds__(256)
void cvt_w(const float* __restrict__ Wq, const float* __restrict__ Wk,
           const float* __restrict__ Ww, unsigned short* __restrict__ Wc)
{
    const int r = blockIdx.x;
    const int c0 = threadIdx.x * 8;
    const float* src = nullptr;
    if (r < 256)      src = Wq + (size_t)r * HID;
    else if (r < 320) src = Wk + (size_t)(r - 256) * HID;
    else if (r < 324) src = Ww + (size_t)(r - 320) * HID;
    u16x8 o = {0, 0, 0, 0, 0, 0, 0, 0};
    if (src) {
        const float4 a = *(const float4*)(src + c0);
        const float4 b = *(const float4*)(src + c0 + 4);
        o[0] = f2bf(a.x); o[1] = f2bf(a.y); o[2] = f2bf(a.z); o[3] = f2bf(a.w);
        o[4] = f2bf(b.x); o[5] = f2bf(b.y); o[6] = f2bf(b.z); o[7] = f2bf(b.w);
    }
    *(u16x8*)(Wc + (size_t)r * HID + c0) = o;
}

// ============ Kernel 2: MFMA projection GEMM (unchanged) ============
__global__ __launch_bounds__(256)
void proj_mfma(const unsigned short* __restrict__ Xb,
               const unsigned short* __restrict__ Wc,
               const float* __restrict__ bw,
               unsigned short* __restrict__ Qo,
               unsigned short* __restrict__ Ko,
               float* __restrict__ Wo)
{
    __shared__ unsigned short As[128 * 64];
    __shared__ unsigned short Bs[128 * 64];
    const int tid  = threadIdx.x;
    const int row0 = blockIdx.x * 128;
    const int col0 = blockIdx.y * 128;
    const int lane = tid & 63, wid = tid >> 6;
    const int wr = wid >> 1, wc = wid & 1;
    const int sr = tid >> 3, sc = (tid & 7) * 8;
    const int fr = lane & 15, fk = (lane >> 4) * 8;

    f32x4 acc[4][4];
    #pragma unroll
    for (int i = 0; i < 4; ++i)
        #pragma unroll
        for (int j = 0; j < 4; ++j) acc[i][j] = (f32x4){0.f, 0.f, 0.f, 0.f};

    const unsigned short* Ag = Xb + (size_t)(row0 + sr) * HID + sc;
    const unsigned short* Bg = Wc + (size_t)(col0 + sr) * HID + sc;

    for (int kt = 0; kt < HID; kt += 64) {
        __syncthreads();
        #pragma unroll
        for (int c2 = 0; c2 < 4; ++c2) {
            gload16(Ag + (size_t)c2 * 32 * HID + kt, &As[wid * 512 + c2 * 2048]);
            gload16(Bg + (size_t)c2 * 32 * HID + kt, &Bs[wid * 512 + c2 * 2048]);
        }
        __syncthreads();
        #pragma unroll
        for (int kk = 0; kk < 2; ++kk) {
            bf16x8 af[4], bfv[4];
            #pragma unroll
            for (int mi = 0; mi < 4; ++mi)
                af[mi] = *(const bf16x8*)&As[(wr * 64 + mi * 16 + fr) * 64 + kk * 32 + fk];
            #pragma unroll
            for (int ni = 0; ni < 4; ++ni)
                bfv[ni] = *(const bf16x8*)&Bs[(wc * 64 + ni * 16 + fr) * 64 + kk * 32 + fk];
            #pragma unroll
            for (int mi = 0; mi < 4; ++mi)
                #pragma unroll
                for (int ni = 0; ni < 4; ++ni)
                    acc[mi][ni] = __builtin_amdgcn_mfma_f32_16x16x32_bf16(
                        af[mi], bfv[ni], acc[mi][ni], 0, 0, 0);
        }
    }

    const int orow = (lane >> 4) * 4, ocol = lane & 15;
    #pragma unroll
    for (int mi = 0; mi < 4; ++mi) {
        #pragma unroll
        for (int ni = 0; ni < 4; ++ni) {
            const int cg = col0 + wc * 64 + ni * 16 + ocol;
            #pragma unroll
            for (int j = 0; j < 4; ++j) {
                const int rg = row0 + wr * 64 + mi * 16 + orow + j;
                const float v = acc[mi][ni][j];
                if (cg < 256)       Qo[(size_t)rg * 256 + cg] = f2bf(sanef(v));
                else if (cg < 320)  Ko[(size_t)rg * 64 + (cg - 256)] = f2bf(sanef(v));
                else if (cg < 324)  Wo[(size_t)rg * 4 + (cg - 320)] = sanef(sigm(v + bw[cg - 320]));
            }
        }
    }
}

// ============ Kernel 3a: masked-region fill (strict upper 128x128 tiles) ============
// u in [0,496): strict-lower pair (p,q), q<p  ->  (it,jt)=(q,p) is strict-upper.
__global__ __launch_bounds__(256)
void score_fill(float* __restrict__ out)
{
    const int u = blockIdx.x, b = blockIdx.y;
    int p = (int)((sqrtf(8.f * u + 1.f) + 1.f) * 0.5f);
    while (p * (p - 1) / 2 > u) --p;
    while ((p + 1) * p / 2 <= u) ++p;
    const int q = u - p * (p - 1) / 2;
    const size_t obase = ((size_t)b * TSEQ + (size_t)q * 128) * TSEQ + (size_t)p * 128;

    const int tid = threadIdx.x;
    const int row = tid >> 1, half = tid & 1;
    float4* po = (float4*)(out + obase + (size_t)row * TSEQ + half * 64);
    const float4 nh = make_float4(NEG_HUGE, NEG_HUGE, NEG_HUGE, NEG_HUGE);
    #pragma unroll
    for (int i = 0; i < 16; ++i) po[i] = nh;
}

// ============ Kernel 3b: gated causal scores, lower 128x64 tiles only ============
// u = it*(it+1) + jt, jt in [0, 2it+2).  4 waves (2x2), wave tile 64x32.
// K frags head-invariant -> registers; Q double-buffered across heads.
__global__ __launch_bounds__(256, 3)
void score_comp(const unsigned short* __restrict__ Qb,   // [8192][256]
                const unsigned short* __restrict__ Kb,   // [8192][64]
                const float* __restrict__ Wo,            // [8192][4] = sigmoid(w)
                const float* __restrict__ ib,
                float* __restrict__ out)
{
    const int u = blockIdx.x, b = blockIdx.y;
    int it = (int)((sqrtf(4.f * u + 1.f) - 1.f) * 0.5f);
    while (it * it + it > u) --it;
    while ((it + 1) * (it + 1) + (it + 1) <= u) ++it;
    const int jt = u - it * it - it;

    const int row0 = it * 128, col0 = jt * 64;
    const size_t obase = ((size_t)b * TSEQ + row0) * TSEQ + col0;
    const int tid = threadIdx.x;
    const int lane = tid & 63, wid = tid >> 6;
    const int wr = wid >> 1, wc = wid & 1;
    const int fr = lane & 15, fk8 = (lane >> 4) * 8;

    __shared__ float wst[512];               // [128 rows][4 heads]
    wst[tid]       = Wo[((size_t)b * TSEQ + row0) * 4 + tid];
    wst[tid + 256] = Wo[((size_t)b * TSEQ + row0) * 4 + tid + 256];
    __syncthreads();

    const unsigned short* Qp = Qb + ((size_t)(b * TSEQ + row0 + wr * 64 + fr)) * 256 + fk8;
    const unsigned short* Kp = Kb + ((size_t)(b * TSEQ + col0 + wc * 32 + fr)) * 64 + fk8;
    const float4 ibv = *(const float4*)ib;

    bf16x8 kf[2][2];                          // [kk][ni] — reused all heads
    #pragma unroll
    for (int kk = 0; kk < 2; ++kk)
        #pragma unroll
        for (int ni = 0; ni < 2; ++ni)
            kf[kk][ni] = *(const bf16x8*)(Kp + (size_t)ni * 16 * 64 + kk * 32);

    f32x4 fin[4][2];
    #pragma unroll
    for (int i = 0; i < 4; ++i)
        #pragma unroll
        for (int j = 0; j < 2; ++j) fin[i][j] = (f32x4){0.f, 0.f, 0.f, 0.f};

    const float C1 = -SCALE * NLOG2E;

#define LOADQ(QV, h)                                                          \
    _Pragma("unroll")                                                         \
    for (int f = 0; f < 8; ++f)                                               \
        QV[f] = *(const bf16x8*)(Qp + (size_t)(f >> 1) * 16 * 256 + (h) * 64 + (f & 1) * 32);

#define MFMA_FOLD(QV, h, IBC)                                                 \
    {                                                                         \
        f32x4 acc[4][2];                                                      \
        _Pragma("unroll")                                                     \
        for (int i = 0; i < 4; ++i)                                           \
            _Pragma("unroll")                                                 \
            for (int j = 0; j < 2; ++j) acc[i][j] = (f32x4){0.f,0.f,0.f,0.f}; \
        _Pragma("unroll")                                                     \
        for (int kk = 0; kk < 2; ++kk)                                        \
            _Pragma("unroll")                                                 \
            for (int mi = 0; mi < 4; ++mi)                                    \
                _Pragma("unroll")                                             \
                for (int ni = 0; ni < 2; ++ni)                                \
                    acc[mi][ni] = __builtin_amdgcn_mfma_f32_16x16x32_bf16(    \
                        QV[mi * 2 + kk], kf[kk][ni], acc[mi][ni], 0, 0, 0);   \
        NEXTLOAD;                                                             \
        const float c0 = -(IBC) * NLOG2E;                                     \
        _Pragma("unroll")                                                     \
        for (int mi = 0; mi < 4; ++mi)                                        \
            _Pragma("unroll")                                                 \
            for (int j = 0; j < 4; ++j) {                                     \
                const int rloc = wr * 64 + mi * 16 + (lane >> 4) * 4 + j;     \
                const float wsv = wst[rloc * 4 + (h)];                        \
                _Pragma("unroll")                                             \
                for (int ni = 0; ni < 2; ++ni) {                              \
                    const float t = fmaf(acc[mi][ni][j], C1, c0);             \
                    const float g = __builtin_amdgcn_rcpf(1.0f + exp2f(t));   \
                    fin[mi][ni][j] += g * wsv;                                \
                }                                                             \
            }                                                                 \
    }

    bf16x8 qa[8], qb[8];
    LOADQ(qa, 0);
#define NEXTLOAD LOADQ(qb, 1)
    MFMA_FOLD(qa, 0, ibv.x);
#undef NEXTLOAD
#define NEXTLOAD LOADQ(qa, 2)
    MFMA_FOLD(qb, 1, ibv.y);
#undef NEXTLOAD
#define NEXTLOAD LOADQ(qb, 3)
    MFMA_FOLD(qa, 2, ibv.z);
#undef NEXTLOAD
#define NEXTLOAD
    MFMA_FOLD(qb, 3, ibv.w);
#undef NEXTLOAD

    const bool diag = (col0 + 63 > row0);
    #pragma unroll
    for (int mi = 0; mi < 4; ++mi) {
        #pragma unroll
        for (int j = 0; j < 4; ++j) {
            const int rloc = wr * 64 + mi * 16 + (lane >> 4) * 4 + j;
            #pragma unroll
            for (int ni = 0; ni < 2; ++ni) {
                const int cloc = wc * 32 + ni * 16 + fr;
                float v = sanef(fin[mi][ni][j]);
                if (diag && (col0 + cloc > row0 + rloc)) v = NEG_HUGE;
                out[obase + (size_t)rloc * TSEQ + cloc] = v;
            }
        }
    }
}

extern "C" void kernel_launch(void* const* d_in, const int* in_sizes, int n_in,
                              void* d_out, int out_size, void* d_ws, size_t ws_size,
                              hipStream_t stream)
{
    const float* x  = (const float*)d_in[0];
    const float* Wq = (const float*)d_in[1];
    const float* Wk = (const float*)d_in[2];
    const float* Ww = (const float*)d_in[3];
    const float* bw = (const float*)d_in[4];
    const float* ib = (const float*)d_in[5];
    float* out = (float*)d_out;

    unsigned short* Xb = (unsigned short*)d_ws;            // 32 MB
    unsigned short* Wc = Xb + (size_t)NROW * HID;          // 1.5 MB
    unsigned short* Qo = Wc + (size_t)384 * HID;           // 4 MB
    unsigned short* Ko = Qo + (size_t)NROW * 256;          // 1 MB
    float*          Wo = (float*)(Ko + (size_t)NROW * 64); // 128 KB

    cvt_x<<<dim3(2048), dim3(256), 0, stream>>>(x, Xb);
    cvt_w<<<dim3(384), dim3(256), 0, stream>>>(Wq, Wk, Ww, Wc);
    proj_mfma<<<dim3(NROW / 128, 3), dim3(256), 0, stream>>>(Xb, Wc, bw, Qo, Ko, Wo);
    score_fill<<<dim3(496, NB), dim3(256), 0, stream>>>(out);
    score_comp<<<dim3(1056, NB), dim3(256), 0, stream>>>(Qo, Ko, Wo, ib, out);
}

// Round 7
// 133.894 us; speedup vs baseline: 1.5208x; 1.0870x over previous
//
#include <hip/hip_runtime.h>
#include <cmath>

typedef __attribute__((ext_vector_type(4))) float f32x4;
typedef __attribute__((ext_vector_type(8))) short bf16x8;
typedef __attribute__((ext_vector_type(8))) unsigned short u16x8;

#define TSEQ 4096
#define NB 2
#define HID 2048
#define DD 64
#define NH 4
#define NROW 8192
#define SCALE 0.125f
#define NEG_HUGE -3.3e38f
#define LOG2E 1.4426950408889634f

#if __has_builtin(__builtin_amdgcn_exp2f)
#define EXP2(x) __builtin_amdgcn_exp2f(x)
#else
#define EXP2(x) exp2f(x)
#endif

__device__ __forceinline__ float sanef(float v) {
    return fminf(fmaxf(v, -3.3e38f), 3.3e38f);   // NaN->-3.3e38, +/-inf clamped
}
__device__ __forceinline__ unsigned short f2bf(float f) {  // RNE fp32->bf16
    unsigned int u = __float_as_uint(f);
    unsigned int r = u + 0x7FFF + ((u >> 16) & 1);
    return (unsigned short)(r >> 16);
}
__device__ __forceinline__ float sigm(float z) {
    return 1.0f / (1.0f + __expf(-z));
}
__device__ __forceinline__ void gload16(const unsigned short* g, unsigned short* l) {
    __builtin_amdgcn_global_load_lds(
        (const __attribute__((address_space(1))) void*)g,
        (__attribute__((address_space(3))) void*)l, 16, 0, 0);
}

// ============ Kernel 1a: x fp32 -> bf16 ============
__global__ __launch_bounds__(256)
void cvt_x(const float* __restrict__ x, unsigned short* __restrict__ xb)
{
    const size_t t = (size_t)blockIdx.x * 256 + threadIdx.x;
    #pragma unroll
    for (int i = 0; i < 4; ++i) {
        const size_t base = t * 32 + (size_t)i * 8;
        const float4 a = *(const float4*)(x + base);
        const float4 b = *(const float4*)(x + base + 4);
        u16x8 o;
        o[0] = f2bf(a.x); o[1] = f2bf(a.y); o[2] = f2bf(a.z); o[3] = f2bf(a.w);
        o[4] = f2bf(b.x); o[5] = f2bf(b.y); o[6] = f2bf(b.z); o[7] = f2bf(b.w);
        *(u16x8*)(xb + base) = o;
    }
}

// ============ Kernel 1b: weight concat [384][2048] bf16 ============
__global__ __launch_bounds__(256)
void cvt_w(const float* __restrict__ Wq, const float* __restrict__ Wk,
           const float* __restrict__ Ww, unsigned short* __restrict__ Wc)
{
    const int r = blockIdx.x;
    const int c0 = threadIdx.x * 8;
    const float* src = nullptr;
    if (r < 256)      src = Wq + (size_t)r * HID;
    else if (r < 320) src = Wk + (size_t)(r - 256) * HID;
    else if (r < 324) src = Ww + (size_t)(r - 320) * HID;
    u16x8 o = {0, 0, 0, 0, 0, 0, 0, 0};
    if (src) {
        const float4 a = *(const float4*)(src + c0);
        const float4 b = *(const float4*)(src + c0 + 4);
        o[0] = f2bf(a.x); o[1] = f2bf(a.y); o[2] = f2bf(a.z); o[3] = f2bf(a.w);
        o[4] = f2bf(b.x); o[5] = f2bf(b.y); o[6] = f2bf(b.z); o[7] = f2bf(b.w);
    }
    *(u16x8*)(Wc + (size_t)r * HID + c0) = o;
}

// ============ Kernel 2: MFMA projection GEMM ============
// 64x128 tiles, grid 384 (1D) with XCD-chunked remap: the 3 col-blocks of a
// row-panel run consecutively on one XCD -> x panel L2-hits (HBM x-read ~1x).
__global__ __launch_bounds__(256)
void proj_mfma(const unsigned short* __restrict__ Xb,
               const unsigned short* __restrict__ Wc,
               const float* __restrict__ bw,
               unsigned short* __restrict__ Qo,
               unsigned short* __restrict__ Ko,
               float* __restrict__ Wo)
{
    __shared__ unsigned short As[64 * 64];
    __shared__ unsigned short Bs[128 * 64];
    const int bid = blockIdx.x;
    const int w   = (bid & 7) * 48 + (bid >> 3);     // 384 = 8 * 48, bijective
    const int row0 = (w / 3) * 64;
    const int col0 = (w % 3) * 128;

    const int tid  = threadIdx.x;
    const int lane = tid & 63, wid = tid >> 6;
    const int wr = wid >> 1, wc = wid & 1;           // wave tile 32x64
    const int sr = tid >> 3, sc = (tid & 7) * 8;
    const int fr = lane & 15, fk = (lane >> 4) * 8;

    f32x4 acc[2][4];
    #pragma unroll
    for (int i = 0; i < 2; ++i)
        #pragma unroll
        for (int j = 0; j < 4; ++j) acc[i][j] = (f32x4){0.f, 0.f, 0.f, 0.f};

    const unsigned short* Ag = Xb + (size_t)(row0 + sr) * HID + sc;
    const unsigned short* Bg = Wc + (size_t)(col0 + sr) * HID + sc;

    for (int kt = 0; kt < HID; kt += 64) {
        __syncthreads();
        #pragma unroll
        for (int c2 = 0; c2 < 2; ++c2)
            gload16(Ag + (size_t)c2 * 32 * HID + kt, &As[wid * 512 + c2 * 2048]);
        #pragma unroll
        for (int c2 = 0; c2 < 4; ++c2)
            gload16(Bg + (size_t)c2 * 32 * HID + kt, &Bs[wid * 512 + c2 * 2048]);
        __syncthreads();
        #pragma unroll
        for (int kk = 0; kk < 2; ++kk) {
            bf16x8 af[2], bfv[4];
            #pragma unroll
            for (int mi = 0; mi < 2; ++mi)
                af[mi] = *(const bf16x8*)&As[(wr * 32 + mi * 16 + fr) * 64 + kk * 32 + fk];
            #pragma unroll
            for (int ni = 0; ni < 4; ++ni)
                bfv[ni] = *(const bf16x8*)&Bs[(wc * 64 + ni * 16 + fr) * 64 + kk * 32 + fk];
            #pragma unroll
            for (int mi = 0; mi < 2; ++mi)
                #pragma unroll
                for (int ni = 0; ni < 4; ++ni)
                    acc[mi][ni] = __builtin_amdgcn_mfma_f32_16x16x32_bf16(
                        af[mi], bfv[ni], acc[mi][ni], 0, 0, 0);
        }
    }

    const int orow = (lane >> 4) * 4, ocol = lane & 15;
    #pragma unroll
    for (int mi = 0; mi < 2; ++mi) {
        #pragma unroll
        for (int ni = 0; ni < 4; ++ni) {
            const int cg = col0 + wc * 64 + ni * 16 + ocol;
            #pragma unroll
            for (int j = 0; j < 4; ++j) {
                const int rg = row0 + wr * 32 + mi * 16 + orow + j;
                const float v = acc[mi][ni][j];
                if (cg < 256)       Qo[(size_t)rg * 256 + cg] = f2bf(sanef(v));
                else if (cg < 320)  Ko[(size_t)rg * 64 + (cg - 256)] = f2bf(sanef(v));
                else if (cg < 324)  Wo[(size_t)rg * 4 + (cg - 320)] = sanef(sigm(v + bw[cg - 320]));
            }
        }
    }
}

// ============ Kernel 3a: masked-region fill (strict upper 128x128 tiles) ============
__global__ __launch_bounds__(256)
void score_fill(float* __restrict__ out)
{
    const int u = blockIdx.x, b = blockIdx.y;
    int p = (int)((sqrtf(8.f * u + 1.f) + 1.f) * 0.5f);
    while (p * (p - 1) / 2 > u) --p;
    while ((p + 1) * p / 2 <= u) ++p;
    const int q = u - p * (p - 1) / 2;
    const size_t obase = ((size_t)b * TSEQ + (size_t)q * 128) * TSEQ + (size_t)p * 128;

    const int tid = threadIdx.x;
    const int row = tid >> 1, half = tid & 1;
    float4* po = (float4*)(out + obase + (size_t)row * TSEQ + half * 64);
    const float4 nh = make_float4(NEG_HUGE, NEG_HUGE, NEG_HUGE, NEG_HUGE);
    #pragma unroll
    for (int i = 0; i < 16; ++i) po[i] = nh;
}

// ============ Kernel 3b: gated causal scores, lower 128x64 tiles ============
// 4 waves (2x2), wave tile 64x32. K frags in regs all heads; Q double-buffered.
// (256,2): VGPR cap 256 — footprint ~170, must NOT spill (the round-6 risk).
__global__ __launch_bounds__(256, 2)
void score_comp(const unsigned short* __restrict__ Qb,   // [8192][256]
                const unsigned short* __restrict__ Kb,   // [8192][64]
                const float* __restrict__ Wo,            // [8192][4] = sigmoid(w)
                const float* __restrict__ ib,
                float* __restrict__ out)
{
    // XCD-chunked remap: 2112 = 8 * 264 blocks; batch b and nearby it-rows
    // stay on one XCD -> K_b (1 MB) and Q panels L2-resident.
    const int bid = blockIdx.x;
    const int w   = (bid & 7) * 264 + (bid >> 3);
    const int b   = w / 1056;
    const int u   = w % 1056;
    int it = (int)((sqrtf(4.f * u + 1.f) - 1.f) * 0.5f);
    while (it * it + it > u) --it;
    while ((it + 1) * (it + 1) + (it + 1) <= u) ++it;
    const int jt = u - it * it - it;

    const int row0 = it * 128, col0 = jt * 64;
    const size_t obase = ((size_t)b * TSEQ + row0) * TSEQ + col0;
    const int tid = threadIdx.x;
    const int lane = tid & 63, wid = tid >> 6;
    const int wr = wid >> 1, wc = wid & 1;
    const int fr = lane & 15, fk8 = (lane >> 4) * 8;

    __shared__ float wst[512];               // [128 rows][4 heads]
    wst[tid]       = Wo[((size_t)b * TSEQ + row0) * 4 + tid];
    wst[tid + 256] = Wo[((size_t)b * TSEQ + row0) * 4 + tid + 256];
    __syncthreads();

    const unsigned short* Qp = Qb + ((size_t)(b * TSEQ + row0 + wr * 64 + fr)) * 256 + fk8;
    const unsigned short* Kp = Kb + ((size_t)(b * TSEQ + col0 + wc * 32 + fr)) * 64 + fk8;
    const float4 ibv = *(const float4*)ib;

    bf16x8 kf[2][2];                          // [kk][ni] — reused all heads
    #pragma unroll
    for (int kk = 0; kk < 2; ++kk)
        #pragma unroll
        for (int ni = 0; ni < 2; ++ni)
            kf[kk][ni] = *(const bf16x8*)(Kp + (size_t)ni * 16 * 64 + kk * 32);

    f32x4 fin[4][2];
    #pragma unroll
    for (int i = 0; i < 4; ++i)
        #pragma unroll
        for (int j = 0; j < 2; ++j) fin[i][j] = (f32x4){0.f, 0.f, 0.f, 0.f};

    const float C1 = -SCALE * LOG2E;

#define LOADQ(QV, h)                                                          \
    _Pragma("unroll")                                                         \
    for (int f = 0; f < 8; ++f)                                               \
        QV[f] = *(const bf16x8*)(Qp + (size_t)(f >> 1) * 16 * 256 + (h) * 64 + (f & 1) * 32);

// g = sigmoid(acc*SCALE + ib_h) = rcp(1 + exp2(acc*C1 + c0)); g in [0,1],
// ws in [0,1] -> fin in [0,4]: finite by construction, no sanitizer needed.
#define MFMA_FOLD(QV, h, IBC)                                                 \
    {                                                                         \
        f32x4 acc[4][2];                                                      \
        _Pragma("unroll")                                                     \
        for (int i = 0; i < 4; ++i)                                           \
            _Pragma("unroll")                                                 \
            for (int j = 0; j < 2; ++j) acc[i][j] = (f32x4){0.f,0.f,0.f,0.f}; \
        _Pragma("unroll")                                                     \
        for (int kk = 0; kk < 2; ++kk)                                        \
            _Pragma("unroll")                                                 \
            for (int mi = 0; mi < 4; ++mi)                                    \
                _Pragma("unroll")                                             \
                for (int ni = 0; ni < 2; ++ni)                                \
                    acc[mi][ni] = __builtin_amdgcn_mfma_f32_16x16x32_bf16(    \
                        QV[mi * 2 + kk], kf[kk][ni], acc[mi][ni], 0, 0, 0);   \
        NEXTLOAD;                                                             \
        const float c0 = -(IBC) * LOG2E;                                      \
        _Pragma("unroll")                                                     \
        for (int mi = 0; mi < 4; ++mi)                                        \
            _Pragma("unroll")                                                 \
            for (int j = 0; j < 4; ++j) {                                     \
                const int rloc = wr * 64 + mi * 16 + (lane >> 4) * 4 + j;     \
                const float wsv = wst[rloc * 4 + (h)];                        \
                _Pragma("unroll")                                             \
                for (int ni = 0; ni < 2; ++ni) {                              \
                    const float t = fmaf(acc[mi][ni][j], C1, c0);             \
                    const float g = __builtin_amdgcn_rcpf(1.0f + EXP2(t));    \
                    fin[mi][ni][j] += g * wsv;                                \
                }                                                             \
            }                                                                 \
    }

    bf16x8 qa[8], qb[8];
    LOADQ(qa, 0);
#define NEXTLOAD LOADQ(qb, 1)
    MFMA_FOLD(qa, 0, ibv.x);
#undef NEXTLOAD
#define NEXTLOAD LOADQ(qa, 2)
    MFMA_FOLD(qb, 1, ibv.y);
#undef NEXTLOAD
#define NEXTLOAD LOADQ(qb, 3)
    MFMA_FOLD(qa, 2, ibv.z);
#undef NEXTLOAD
#define NEXTLOAD
    MFMA_FOLD(qb, 3, ibv.w);
#undef NEXTLOAD

    const bool diag = (col0 + 63 > row0);
    #pragma unroll
    for (int mi = 0; mi < 4; ++mi) {
        #pragma unroll
        for (int j = 0; j < 4; ++j) {
            const int rloc = wr * 64 + mi * 16 + (lane >> 4) * 4 + j;
            #pragma unroll
            for (int ni = 0; ni < 2; ++ni) {
                const int cloc = wc * 32 + ni * 16 + fr;
                float v = fin[mi][ni][j];
                if (diag && (col0 + cloc > row0 + rloc)) v = NEG_HUGE;
                out[obase + (size_t)rloc * TSEQ + cloc] = v;
            }
        }
    }
}

extern "C" void kernel_launch(void* const* d_in, const int* in_sizes, int n_in,
                              void* d_out, int out_size, void* d_ws, size_t ws_size,
                              hipStream_t stream)
{
    const float* x  = (const float*)d_in[0];
    const float* Wq = (const float*)d_in[1];
    const float* Wk = (const float*)d_in[2];
    const float* Ww = (const float*)d_in[3];
    const float* bw = (const float*)d_in[4];
    const float* ib = (const float*)d_in[5];
    float* out = (float*)d_out;

    unsigned short* Xb = (unsigned short*)d_ws;            // 32 MB
    unsigned short* Wc = Xb + (size_t)NROW * HID;          // 1.5 MB
    unsigned short* Qo = Wc + (size_t)384 * HID;           // 4 MB
    unsigned short* Ko = Qo + (size_t)NROW * 256;          // 1 MB
    float*          Wo = (float*)(Ko + (size_t)NROW * 64); // 128 KB

    cvt_x<<<dim3(2048), dim3(256), 0, stream>>>(x, Xb);
    cvt_w<<<dim3(384), dim3(256), 0, stream>>>(Wq, Wk, Ww, Wc);
    proj_mfma<<<dim3(384), dim3(256), 0, stream>>>(Xb, Wc, bw, Qo, Ko, Wo);
    score_fill<<<dim3(496, NB), dim3(256), 0, stream>>>(out);
    score_comp<<<dim3(2112), dim3(256), 0, stream>>>(Qo, Ko, Wo, ib, out);
}

// Round 8
// 118.978 us; speedup vs baseline: 1.7115x; 1.1254x over previous
//
#include <hip/hip_runtime.h>
#include <cmath>

typedef __attribute__((ext_vector_type(4))) float f32x4;
typedef __attribute__((ext_vector_type(8))) short bf16x8;
typedef __attribute__((ext_vector_type(8))) unsigned short u16x8;

#define TSEQ 4096
#define NB 2
#define HID 2048
#define DD 64
#define NH 4
#define NROW 8192
#define SCALE 0.125f
#define NEG_HUGE -3.3e38f
#define LOG2E 1.4426950408889634f

#if __has_builtin(__builtin_amdgcn_exp2f)
#define EXP2(x) __builtin_amdgcn_exp2f(x)
#else
#define EXP2(x) exp2f(x)
#endif

__device__ __forceinline__ float sanef(float v) {
    return fminf(fmaxf(v, -3.3e38f), 3.3e38f);   // NaN->-3.3e38, +/-inf clamped
}
__device__ __forceinline__ unsigned short f2bf(float f) {  // RNE fp32->bf16
    unsigned int u = __float_as_uint(f);
    unsigned int r = u + 0x7FFF + ((u >> 16) & 1);
    return (unsigned short)(r >> 16);
}
__device__ __forceinline__ float sigm(float z) {
    return 1.0f / (1.0f + __expf(-z));
}
__device__ __forceinline__ void gload16(const unsigned short* g, unsigned short* l) {
    __builtin_amdgcn_global_load_lds(
        (const __attribute__((address_space(1))) void*)g,
        (__attribute__((address_space(3))) void*)l, 16, 0, 0);
}

// ============ Kernel 1: weight concat [384][2048] bf16 ============
__global__ __launch_bounds__(256)
void cvt_w(const float* __restrict__ Wq, const float* __restrict__ Wk,
           const float* __restrict__ Ww, unsigned short* __restrict__ Wc)
{
    const int r = blockIdx.x;
    const int c0 = threadIdx.x * 8;
    const float* src = nullptr;
    if (r < 256)      src = Wq + (size_t)r * HID;
    else if (r < 320) src = Wk + (size_t)(r - 256) * HID;
    else if (r < 324) src = Ww + (size_t)(r - 320) * HID;
    u16x8 o = {0, 0, 0, 0, 0, 0, 0, 0};
    if (src) {
        const float4 a = *(const float4*)(src + c0);
        const float4 b = *(const float4*)(src + c0 + 4);
        o[0] = f2bf(a.x); o[1] = f2bf(a.y); o[2] = f2bf(a.z); o[3] = f2bf(a.w);
        o[4] = f2bf(b.x); o[5] = f2bf(b.y); o[6] = f2bf(b.z); o[7] = f2bf(b.w);
    }
    *(u16x8*)(Wc + (size_t)r * HID + c0) = o;
}

// ============ Kernel 2: fused cvt_x + projection GEMM ============
// 64x128 tiles; A reg-staged from fp32 x (convert in-reg, XOR-swizzled LDS
// write); B via global_load_lds with pre-swizzled SOURCE (rule #21: linear
// dest + inverse-swizzled src + swizzled read). Swizzle: 16B chunk c of row r
// lives at chunk c ^ (r&7)  ->  fragment reads are <=2-way bank conflicts.
__global__ __launch_bounds__(256)
void proj_mfma(const float* __restrict__ x,
               const unsigned short* __restrict__ Wc,
               const float* __restrict__ bw,
               unsigned short* __restrict__ Qo,
               unsigned short* __restrict__ Ko,
               float* __restrict__ Wo)
{
    __shared__ unsigned short As[64 * 64];    // 8 KB
    __shared__ unsigned short Bs[128 * 64];   // 16 KB
    const int bid = blockIdx.x;
    const int w   = (bid & 7) * 48 + (bid >> 3);     // 384 = 8*48, bijective
    const int row0 = (w / 3) * 64;
    const int col0 = (w % 3) * 128;

    const int tid  = threadIdx.x;
    const int lane = tid & 63, wid = tid >> 6;
    const int wr = wid >> 1, wc = wid & 1;           // wave tile 32x64
    const int fr = lane & 15;

    // A staging: thread -> row ar (0..63), 16 fp32 cols at (tid&3)*16
    const int ar = tid >> 2, ac2 = (tid & 3) * 2, asw = ar & 7;
    const float* Axg = x + (size_t)(row0 + ar) * HID + (tid & 3) * 16;

    // B staging source: pre-swizzled column chunk
    const int sr = tid >> 3;
    const int scs = ((tid & 7) ^ (sr & 7)) * 8;
    const unsigned short* Bg = Wc + (size_t)(col0 + sr) * HID + scs;

    f32x4 acc[2][4];
    #pragma unroll
    for (int i = 0; i < 2; ++i)
        #pragma unroll
        for (int j = 0; j < 4; ++j) acc[i][j] = (f32x4){0.f, 0.f, 0.f, 0.f};

    for (int kt = 0; kt < HID; kt += 64) {
        __syncthreads();
        #pragma unroll
        for (int c2 = 0; c2 < 4; ++c2)
            gload16(Bg + (size_t)c2 * 32 * HID + kt, &Bs[wid * 512 + c2 * 2048]);
        const float4 a0 = *(const float4*)(Axg + kt);
        const float4 a1 = *(const float4*)(Axg + kt + 4);
        const float4 a2 = *(const float4*)(Axg + kt + 8);
        const float4 a3 = *(const float4*)(Axg + kt + 12);
        u16x8 c0, c1;
        c0[0] = f2bf(a0.x); c0[1] = f2bf(a0.y); c0[2] = f2bf(a0.z); c0[3] = f2bf(a0.w);
        c0[4] = f2bf(a1.x); c0[5] = f2bf(a1.y); c0[6] = f2bf(a1.z); c0[7] = f2bf(a1.w);
        c1[0] = f2bf(a2.x); c1[1] = f2bf(a2.y); c1[2] = f2bf(a2.z); c1[3] = f2bf(a2.w);
        c1[4] = f2bf(a3.x); c1[5] = f2bf(a3.y); c1[6] = f2bf(a3.z); c1[7] = f2bf(a3.w);
        *(u16x8*)&As[ar * 64 + ((ac2    ) ^ asw) * 8] = c0;
        *(u16x8*)&As[ar * 64 + ((ac2 + 1) ^ asw) * 8] = c1;
        __syncthreads();
        #pragma unroll
        for (int kk = 0; kk < 2; ++kk) {
            const int chnk = ((kk * 4 + (lane >> 4)) ^ (fr & 7)) * 8;
            bf16x8 af[2], bfv[4];
            #pragma unroll
            for (int mi = 0; mi < 2; ++mi)
                af[mi] = *(const bf16x8*)&As[(wr * 32 + mi * 16 + fr) * 64 + chnk];
            #pragma unroll
            for (int ni = 0; ni < 4; ++ni)
                bfv[ni] = *(const bf16x8*)&Bs[(wc * 64 + ni * 16 + fr) * 64 + chnk];
            #pragma unroll
            for (int mi = 0; mi < 2; ++mi)
                #pragma unroll
                for (int ni = 0; ni < 4; ++ni)
                    acc[mi][ni] = __builtin_amdgcn_mfma_f32_16x16x32_bf16(
                        af[mi], bfv[ni], acc[mi][ni], 0, 0, 0);
        }
    }

    const int orow = (lane >> 4) * 4, ocol = lane & 15;
    #pragma unroll
    for (int mi = 0; mi < 2; ++mi) {
        #pragma unroll
        for (int ni = 0; ni < 4; ++ni) {
            const int cg = col0 + wc * 64 + ni * 16 + ocol;
            #pragma unroll
            for (int j = 0; j < 4; ++j) {
                const int rg = row0 + wr * 32 + mi * 16 + orow + j;
                const float v = acc[mi][ni][j];
                if (cg < 256)       Qo[(size_t)rg * 256 + cg] = f2bf(sanef(v));
                else if (cg < 320)  Ko[(size_t)rg * 64 + (cg - 256)] = f2bf(sanef(v));
                else if (cg < 324)  Wo[(size_t)rg * 4 + (cg - 320)] = sanef(sigm(v + bw[cg - 320]));
            }
        }
    }
}

// ============ Kernel 3: merged scores (comp 128x64 tiles + fill 128x128) ============
// 3104 = 8*388 blocks, XCD-bijective. w<2112: compute; else masked fill.
// Fill (BW-bound) overlaps compute (VALU/trans-bound) across the device.
__global__ __launch_bounds__(256, 3)
void score_all(const unsigned short* __restrict__ Qb,   // [8192][256]
               const unsigned short* __restrict__ Kb,   // [8192][64]
               const float* __restrict__ Wo,            // [8192][4] = sigmoid(w)
               const float* __restrict__ ib,
               float* __restrict__ out)
{
    const int bid = blockIdx.x;
    const int w   = (bid & 7) * 388 + (bid >> 3);
    const int tid = threadIdx.x;

    if (w >= 2112) {                 // ---- fill path: strict-upper 128x128 ----
        const int v = w - 2112;
        const int b = v / 496, u = v % 496;
        int p = (int)((sqrtf(8.f * u + 1.f) + 1.f) * 0.5f);
        while (p * (p - 1) / 2 > u) --p;
        while ((p + 1) * p / 2 <= u) ++p;
        const int q = u - p * (p - 1) / 2;
        const size_t obase = ((size_t)b * TSEQ + (size_t)q * 128) * TSEQ + (size_t)p * 128;
        const int row = tid >> 1, half = tid & 1;
        float4* po = (float4*)(out + obase + (size_t)row * TSEQ + half * 64);
        const float4 nh = make_float4(NEG_HUGE, NEG_HUGE, NEG_HUGE, NEG_HUGE);
        #pragma unroll
        for (int i = 0; i < 16; ++i) po[i] = nh;
        return;
    }

    // ---- compute path: lower 128x64 tile ----
    const int b = w / 1056, u = w % 1056;
    int it = (int)((sqrtf(4.f * u + 1.f) - 1.f) * 0.5f);
    while (it * it + it > u) --it;
    while ((it + 1) * (it + 1) + (it + 1) <= u) ++it;
    const int jt = u - it * it - it;

    const int row0 = it * 128, col0 = jt * 64;
    const size_t obase = ((size_t)b * TSEQ + row0) * TSEQ + col0;
    const int lane = tid & 63, wid = tid >> 6;
    const int wr = wid >> 1, wc = wid & 1;
    const int fr = lane & 15, fk8 = (lane >> 4) * 8;

    __shared__ float wst[512];               // [128 rows][4 heads]
    wst[tid]       = Wo[((size_t)b * TSEQ + row0) * 4 + tid];
    wst[tid + 256] = Wo[((size_t)b * TSEQ + row0) * 4 + tid + 256];
    __syncthreads();

    const unsigned short* Qp = Qb + ((size_t)(b * TSEQ + row0 + wr * 64 + fr)) * 256 + fk8;
    const unsigned short* Kp = Kb + ((size_t)(b * TSEQ + col0 + wc * 32 + fr)) * 64 + fk8;
    const float4 ibv = *(const float4*)ib;
    const float iba[4] = {ibv.x, ibv.y, ibv.z, ibv.w};

    bf16x8 kf[2][2];                          // [kk][ni] — reused all heads
    #pragma unroll
    for (int kk = 0; kk < 2; ++kk)
        #pragma unroll
        for (int ni = 0; ni < 2; ++ni)
            kf[kk][ni] = *(const bf16x8*)(Kp + (size_t)ni * 16 * 64 + kk * 32);

    f32x4 fin[4][2];
    #pragma unroll
    for (int i = 0; i < 4; ++i)
        #pragma unroll
        for (int j = 0; j < 2; ++j) fin[i][j] = (f32x4){0.f, 0.f, 0.f, 0.f};

    const float C1 = -SCALE * LOG2E;

    #pragma unroll
    for (int h = 0; h < NH; ++h) {
        bf16x8 qv[8];
        #pragma unroll
        for (int f = 0; f < 8; ++f)
            qv[f] = *(const bf16x8*)(Qp + (size_t)(f >> 1) * 16 * 256 + h * 64 + (f & 1) * 32);

        f32x4 acc[4][2];
        #pragma unroll
        for (int i = 0; i < 4; ++i)
            #pragma unroll
            for (int j = 0; j < 2; ++j) acc[i][j] = (f32x4){0.f, 0.f, 0.f, 0.f};
        #pragma unroll
        for (int kk = 0; kk < 2; ++kk)
            #pragma unroll
            for (int mi = 0; mi < 4; ++mi)
                #pragma unroll
                for (int ni = 0; ni < 2; ++ni)
                    acc[mi][ni] = __builtin_amdgcn_mfma_f32_16x16x32_bf16(
                        qv[mi * 2 + kk], kf[kk][ni], acc[mi][ni], 0, 0, 0);

        // g = sigmoid(acc*SCALE+ib) = rcp(1+exp2(acc*C1+c0)); g,ws in [0,1]
        // -> fin finite by construction, no sanitizer needed in hot loop.
        const float c0 = -iba[h] * LOG2E;
        #pragma unroll
        for (int mi = 0; mi < 4; ++mi)
            #pragma unroll
            for (int j = 0; j < 4; ++j) {
                const int rloc = wr * 64 + mi * 16 + (lane >> 4) * 4 + j;
                const float wsv = wst[rloc * 4 + h];
                #pragma unroll
                for (int ni = 0; ni < 2; ++ni) {
                    const float t = fmaf(acc[mi][ni][j], C1, c0);
                    const float g = __builtin_amdgcn_rcpf(1.0f + EXP2(t));
                    fin[mi][ni][j] += g * wsv;
                }
            }
    }

    const bool diag = (col0 + 63 > row0);
    #pragma unroll
    for (int mi = 0; mi < 4; ++mi) {
        #pragma unroll
        for (int j = 0; j < 4; ++j) {
            const int rloc = wr * 64 + mi * 16 + (lane >> 4) * 4 + j;
            #pragma unroll
            for (int ni = 0; ni < 2; ++ni) {
                const int cloc = wc * 32 + ni * 16 + fr;
                float v = fin[mi][ni][j];
                if (diag && (col0 + cloc > row0 + rloc)) v = NEG_HUGE;
                out[obase + (size_t)rloc * TSEQ + cloc] = v;
            }
        }
    }
}

extern "C" void kernel_launch(void* const* d_in, const int* in_sizes, int n_in,
                              void* d_out, int out_size, void* d_ws, size_t ws_size,
                              hipStream_t stream)
{
    const float* x  = (const float*)d_in[0];
    const float* Wq = (const float*)d_in[1];
    const float* Wk = (const float*)d_in[2];
    const float* Ww = (const float*)d_in[3];
    const float* bw = (const float*)d_in[4];
    const float* ib = (const float*)d_in[5];
    float* out = (float*)d_out;

    unsigned short* Wc = (unsigned short*)d_ws;            // 1.5 MB
    unsigned short* Qo = Wc + (size_t)384 * HID;           // 4 MB
    unsigned short* Ko = Qo + (size_t)NROW * 256;          // 1 MB
    float*          Wo = (float*)(Ko + (size_t)NROW * 64); // 128 KB

    cvt_w<<<dim3(384), dim3(256), 0, stream>>>(Wq, Wk, Ww, Wc);
    proj_mfma<<<dim3(384), dim3(256), 0, stream>>>(x, Wc, bw, Qo, Ko, Wo);
    score_all<<<dim3(3104), dim3(256), 0, stream>>>(Qo, Ko, Wo, ib, out);
}

// Round 9
// 112.589 us; speedup vs baseline: 1.8086x; 1.0567x over previous
//
#include <hip/hip_runtime.h>
#include <cmath>

typedef __attribute__((ext_vector_type(4))) float f32x4;
typedef __attribute__((ext_vector_type(8))) short bf16x8;
typedef __attribute__((ext_vector_type(8))) unsigned short u16x8;

#define TSEQ 4096
#define NB 2
#define HID 2048
#define DD 64
#define NH 4
#define NROW 8192
#define SCALE 0.125f
#define NEG_HUGE -3.3e38f
#define LOG2E 1.4426950408889634f

#if __has_builtin(__builtin_amdgcn_exp2f)
#define EXP2(x) __builtin_amdgcn_exp2f(x)
#else
#define EXP2(x) exp2f(x)
#endif

__device__ __forceinline__ float sanef(float v) {
    return fminf(fmaxf(v, -3.3e38f), 3.3e38f);   // NaN->-3.3e38, +/-inf clamped
}
__device__ __forceinline__ unsigned short f2bf(float f) {  // RNE fp32->bf16
    unsigned int u = __float_as_uint(f);
    unsigned int r = u + 0x7FFF + ((u >> 16) & 1);
    return (unsigned short)(r >> 16);
}
__device__ __forceinline__ float sigm(float z) {
    return 1.0f / (1.0f + __expf(-z));
}
__device__ __forceinline__ void gload16(const unsigned short* g, unsigned short* l) {
    __builtin_amdgcn_global_load_lds(
        (const __attribute__((address_space(1))) void*)g,
        (__attribute__((address_space(3))) void*)l, 16, 0, 0);
}

// ============ Kernel 1: weight concat [384][2048] bf16 ============
__global__ __launch_bounds__(256)
void cvt_w(const float* __restrict__ Wq, const float* __restrict__ Wk,
           const float* __restrict__ Ww, unsigned short* __restrict__ Wc)
{
    const int r = blockIdx.x;
    const int c0 = threadIdx.x * 8;
    const float* src = nullptr;
    if (r < 256)      src = Wq + (size_t)r * HID;
    else if (r < 320) src = Wk + (size_t)(r - 256) * HID;
    else if (r < 324) src = Ww + (size_t)(r - 320) * HID;
    u16x8 o = {0, 0, 0, 0, 0, 0, 0, 0};
    if (src) {
        const float4 a = *(const float4*)(src + c0);
        const float4 b = *(const float4*)(src + c0 + 4);
        o[0] = f2bf(a.x); o[1] = f2bf(a.y); o[2] = f2bf(a.z); o[3] = f2bf(a.w);
        o[4] = f2bf(b.x); o[5] = f2bf(b.y); o[6] = f2bf(b.z); o[7] = f2bf(b.w);
    }
    *(u16x8*)(Wc + (size_t)r * HID + c0) = o;
}

// ============ Kernel 2: fused cvt_x + projection GEMM, 64x64 tiles ============
// 768 blocks (8x96 XCD-bijective) = 3 blocks/CU, 12 waves/CU. A reg-staged
// from fp32 x (in-reg cvt, XOR-swizzled ds_write); B via global_load_lds with
// pre-swizzled SOURCE (linear dest). Chunk swizzle: c ^= (row&7).
__global__ __launch_bounds__(256)
void proj_mfma(const float* __restrict__ x,
               const unsigned short* __restrict__ Wc,
               const float* __restrict__ bw,
               unsigned short* __restrict__ Qo,
               unsigned short* __restrict__ Ko,
               float* __restrict__ Wo)
{
    __shared__ unsigned short As[64 * 64];    // 8 KB
    __shared__ unsigned short Bs[64 * 64];    // 8 KB
    const int bid = blockIdx.x;
    const int w   = (bid & 7) * 96 + (bid >> 3);     // 768 = 8*96, bijective
    const int row0 = (w / 6) * 64;
    const int col0 = (w % 6) * 64;

    const int tid  = threadIdx.x;
    const int lane = tid & 63, wid = tid >> 6;
    const int wr = wid >> 1, wc = wid & 1;           // wave tile 32x32
    const int fr = lane & 15;

    // A staging: row ar (0..63), 16 fp32 cols at (tid&3)*16
    const int ar = tid >> 2, ac2 = (tid & 3) * 2, asw = ar & 7;
    const float* Axg = x + (size_t)(row0 + ar) * HID + (tid & 3) * 16;

    // B staging: pre-swizzled source column chunk; rows sr = tid>>3 (0..31)
    const int sr = tid >> 3;
    const int scs = ((tid & 7) ^ (sr & 7)) * 8;
    const unsigned short* Bg = Wc + (size_t)(col0 + sr) * HID + scs;

    f32x4 acc[2][2];
    #pragma unroll
    for (int i = 0; i < 2; ++i)
        #pragma unroll
        for (int j = 0; j < 2; ++j) acc[i][j] = (f32x4){0.f, 0.f, 0.f, 0.f};

    for (int kt = 0; kt < HID; kt += 64) {
        const float4 a0 = *(const float4*)(Axg + kt);
        const float4 a1 = *(const float4*)(Axg + kt + 4);
        const float4 a2 = *(const float4*)(Axg + kt + 8);
        const float4 a3 = *(const float4*)(Axg + kt + 12);
        __syncthreads();
        #pragma unroll
        for (int c2 = 0; c2 < 2; ++c2)
            gload16(Bg + (size_t)c2 * 32 * HID + kt, &Bs[wid * 512 + c2 * 2048]);
        u16x8 c0v, c1v;
        c0v[0] = f2bf(a0.x); c0v[1] = f2bf(a0.y); c0v[2] = f2bf(a0.z); c0v[3] = f2bf(a0.w);
        c0v[4] = f2bf(a1.x); c0v[5] = f2bf(a1.y); c0v[6] = f2bf(a1.z); c0v[7] = f2bf(a1.w);
        c1v[0] = f2bf(a2.x); c1v[1] = f2bf(a2.y); c1v[2] = f2bf(a2.z); c1v[3] = f2bf(a2.w);
        c1v[4] = f2bf(a3.x); c1v[5] = f2bf(a3.y); c1v[6] = f2bf(a3.z); c1v[7] = f2bf(a3.w);
        *(u16x8*)&As[ar * 64 + ((ac2    ) ^ asw) * 8] = c0v;
        *(u16x8*)&As[ar * 64 + ((ac2 + 1) ^ asw) * 8] = c1v;
        __syncthreads();
        #pragma unroll
        for (int kk = 0; kk < 2; ++kk) {
            const int chnk = ((kk * 4 + (lane >> 4)) ^ (fr & 7)) * 8;
            bf16x8 af[2], bfv[2];
            #pragma unroll
            for (int mi = 0; mi < 2; ++mi)
                af[mi] = *(const bf16x8*)&As[(wr * 32 + mi * 16 + fr) * 64 + chnk];
            #pragma unroll
            for (int ni = 0; ni < 2; ++ni)
                bfv[ni] = *(const bf16x8*)&Bs[(wc * 32 + ni * 16 + fr) * 64 + chnk];
            #pragma unroll
            for (int mi = 0; mi < 2; ++mi)
                #pragma unroll
                for (int ni = 0; ni < 2; ++ni)
                    acc[mi][ni] = __builtin_amdgcn_mfma_f32_16x16x32_bf16(
                        af[mi], bfv[ni], acc[mi][ni], 0, 0, 0);
        }
    }

    const int orow = (lane >> 4) * 4, ocol = lane & 15;
    #pragma unroll
    for (int mi = 0; mi < 2; ++mi) {
        #pragma unroll
        for (int ni = 0; ni < 2; ++ni) {
            const int cg = col0 + wc * 32 + ni * 16 + ocol;
            #pragma unroll
            for (int j = 0; j < 4; ++j) {
                const int rg = row0 + wr * 32 + mi * 16 + orow + j;
                const float v = acc[mi][ni][j];
                if (cg < 256)       Qo[(size_t)rg * 256 + cg] = f2bf(sanef(v));
                else if (cg < 320)  Ko[(size_t)rg * 64 + (cg - 256)] = f2bf(sanef(v));
                else if (cg < 324)  Wo[(size_t)rg * 4 + (cg - 320)] = sanef(sigm(v + bw[cg - 320]));
            }
        }
    }
}

// ============ Kernel 3: merged scores (comp 128x64 + fill 128x128) ============
// 3104 = 8*388 blocks, XCD-bijective. Q head-double-buffered (the r7 ILP that
// r8's merge dropped — dbuf@2blk beat nodbuf@3blk, so dbuf + 3blk here).
__global__ __launch_bounds__(256, 3)
void score_all(const unsigned short* __restrict__ Qb,   // [8192][256]
               const unsigned short* __restrict__ Kb,   // [8192][64]
               const float* __restrict__ Wo,            // [8192][4] = sigmoid(w)
               const float* __restrict__ ib,
               float* __restrict__ out)
{
    const int bid = blockIdx.x;
    const int w   = (bid & 7) * 388 + (bid >> 3);
    const int tid = threadIdx.x;

    if (w >= 2112) {                 // ---- fill path: strict-upper 128x128 ----
        const int v = w - 2112;
        const int b = v / 496, u = v % 496;
        int p = (int)((sqrtf(8.f * u + 1.f) + 1.f) * 0.5f);
        while (p * (p - 1) / 2 > u) --p;
        while ((p + 1) * p / 2 <= u) ++p;
        const int q = u - p * (p - 1) / 2;
        const size_t obase = ((size_t)b * TSEQ + (size_t)q * 128) * TSEQ + (size_t)p * 128;
        const int row = tid >> 1, half = tid & 1;
        float4* po = (float4*)(out + obase + (size_t)row * TSEQ + half * 64);
        const float4 nh = make_float4(NEG_HUGE, NEG_HUGE, NEG_HUGE, NEG_HUGE);
        #pragma unroll
        for (int i = 0; i < 16; ++i) po[i] = nh;
        return;
    }

    // ---- compute path: lower 128x64 tile ----
    const int b = w / 1056, u = w % 1056;
    int it = (int)((sqrtf(4.f * u + 1.f) - 1.f) * 0.5f);
    while (it * it + it > u) --it;
    while ((it + 1) * (it + 1) + (it + 1) <= u) ++it;
    const int jt = u - it * it - it;

    const int row0 = it * 128, col0 = jt * 64;
    const size_t obase = ((size_t)b * TSEQ + row0) * TSEQ + col0;
    const int lane = tid & 63, wid = tid >> 6;
    const int wr = wid >> 1, wc = wid & 1;
    const int fr = lane & 15, fk8 = (lane >> 4) * 8;

    __shared__ float wst[512];               // [128 rows][4 heads]
    wst[tid]       = Wo[((size_t)b * TSEQ + row0) * 4 + tid];
    wst[tid + 256] = Wo[((size_t)b * TSEQ + row0) * 4 + tid + 256];
    __syncthreads();

    const unsigned short* Qp = Qb + ((size_t)(b * TSEQ + row0 + wr * 64 + fr)) * 256 + fk8;
    const unsigned short* Kp = Kb + ((size_t)(b * TSEQ + col0 + wc * 32 + fr)) * 64 + fk8;
    const float4 ibv = *(const float4*)ib;

    bf16x8 kf[2][2];                          // [kk][ni] — reused all heads
    #pragma unroll
    for (int kk = 0; kk < 2; ++kk)
        #pragma unroll
        for (int ni = 0; ni < 2; ++ni)
            kf[kk][ni] = *(const bf16x8*)(Kp + (size_t)ni * 16 * 64 + kk * 32);

    f32x4 fin[4][2];
    #pragma unroll
    for (int i = 0; i < 4; ++i)
        #pragma unroll
        for (int j = 0; j < 2; ++j) fin[i][j] = (f32x4){0.f, 0.f, 0.f, 0.f};

    const float C1 = -SCALE * LOG2E;

#define LOADQ(QV, h)                                                          \
    _Pragma("unroll")                                                         \
    for (int f = 0; f < 8; ++f)                                               \
        QV[f] = *(const bf16x8*)(Qp + (size_t)(f >> 1) * 16 * 256 + (h) * 64 + (f & 1) * 32);

// g = sigmoid(acc*SCALE+ib) = rcp(1+exp2(acc*C1+c0)); g,ws in [0,1]
// -> fin in [0,4]: finite by construction, no sanitizer in hot loop.
#define MFMA_FOLD(QV, h, IBC)                                                 \
    {                                                                         \
        f32x4 acc[4][2];                                                      \
        _Pragma("unroll")                                                     \
        for (int i = 0; i < 4; ++i)                                           \
            _Pragma("unroll")                                                 \
            for (int j = 0; j < 2; ++j) acc[i][j] = (f32x4){0.f,0.f,0.f,0.f}; \
        _Pragma("unroll")                                                     \
        for (int kk = 0; kk < 2; ++kk)                                        \
            _Pragma("unroll")                                                 \
            for (int mi = 0; mi < 4; ++mi)                                    \
                _Pragma("unroll")                                             \
                for (int ni = 0; ni < 2; ++ni)                                \
                    acc[mi][ni] = __builtin_amdgcn_mfma_f32_16x16x32_bf16(    \
                        QV[mi * 2 + kk], kf[kk][ni], acc[mi][ni], 0, 0, 0);   \
        NEXTLOAD;                                                             \
        const float c0 = -(IBC) * LOG2E;                                      \
        _Pragma("unroll")                                                     \
        for (int mi = 0; mi < 4; ++mi)                                        \
            _Pragma("unroll")                                                 \
            for (int j = 0; j < 4; ++j) {                                     \
                const int rloc = wr * 64 + mi * 16 + (lane >> 4) * 4 + j;     \
                const float wsv = wst[rloc * 4 + (h)];                        \
                _Pragma("unroll")                                             \
                for (int ni = 0; ni < 2; ++ni) {                              \
                    const float t = fmaf(acc[mi][ni][j], C1, c0);             \
                    const float g = __builtin_amdgcn_rcpf(1.0f + EXP2(t));    \
                    fin[mi][ni][j] += g * wsv;                                \
                }                                                             \
            }                                                                 \
    }

    bf16x8 qa[8], qb[8];
    LOADQ(qa, 0);
#define NEXTLOAD LOADQ(qb, 1)
    MFMA_FOLD(qa, 0, ibv.x);
#undef NEXTLOAD
#define NEXTLOAD LOADQ(qa, 2)
    MFMA_FOLD(qb, 1, ibv.y);
#undef NEXTLOAD
#define NEXTLOAD LOADQ(qb, 3)
    MFMA_FOLD(qa, 2, ibv.z);
#undef NEXTLOAD
#define NEXTLOAD
    MFMA_FOLD(qb, 3, ibv.w);
#undef NEXTLOAD

    const bool diag = (col0 + 63 > row0);
    #pragma unroll
    for (int mi = 0; mi < 4; ++mi) {
        #pragma unroll
        for (int j = 0; j < 4; ++j) {
            const int rloc = wr * 64 + mi * 16 + (lane >> 4) * 4 + j;
            #pragma unroll
            for (int ni = 0; ni < 2; ++ni) {
                const int cloc = wc * 32 + ni * 16 + fr;
                float v = fin[mi][ni][j];
                if (diag && (col0 + cloc > row0 + rloc)) v = NEG_HUGE;
                out[obase + (size_t)rloc * TSEQ + cloc] = v;
            }
        }
    }
}

extern "C" void kernel_launch(void* const* d_in, const int* in_sizes, int n_in,
                              void* d_out, int out_size, void* d_ws, size_t ws_size,
                              hipStream_t stream)
{
    const float* x  = (const float*)d_in[0];
    const float* Wq = (const float*)d_in[1];
    const float* Wk = (const float*)d_in[2];
    const float* Ww = (const float*)d_in[3];
    const float* bw = (const float*)d_in[4];
    const float* ib = (const float*)d_in[5];
    float* out = (float*)d_out;

    unsigned short* Wc = (unsigned short*)d_ws;            // 1.5 MB
    unsigned short* Qo = Wc + (size_t)384 * HID;           // 4 MB
    unsigned short* Ko = Qo + (size_t)NROW * 256;          // 1 MB
    float*          Wo = (float*)(Ko + (size_t)NROW * 64); // 128 KB

    cvt_w<<<dim3(384), dim3(256), 0, stream>>>(Wq, Wk, Ww, Wc);
    proj_mfma<<<dim3(768), dim3(256), 0, stream>>>(x, Wc, bw, Qo, Ko, Wo);
    score_all<<<dim3(3104), dim3(256), 0, stream>>>(Qo, Ko, Wo, ib, out);
}

// Round 10
// 102.997 us; speedup vs baseline: 1.9770x; 1.0931x over previous
//
#include <hip/hip_runtime.h>
#include <cmath>

typedef __attribute__((ext_vector_type(4))) float f32x4;
typedef __attribute__((ext_vector_type(8))) short bf16x8;
typedef __attribute__((ext_vector_type(8))) unsigned short u16x8;

#define TSEQ 4096
#define NB 2
#define HID 2048
#define DD 64
#define NH 4
#define NROW 8192
#define SCALE 0.125f
#define NEG_HUGE -3.3e38f
#define LOG2E 1.4426950408889634f

#if __has_builtin(__builtin_amdgcn_exp2f)
#define EXP2(x) __builtin_amdgcn_exp2f(x)
#else
#define EXP2(x) exp2f(x)
#endif

__device__ __forceinline__ float sanef(float v) {
    return fminf(fmaxf(v, -3.3e38f), 3.3e38f);   // NaN->-3.3e38, +/-inf clamped
}
__device__ __forceinline__ unsigned short f2bf(float f) {  // RNE fp32->bf16
    unsigned int u = __float_as_uint(f);
    unsigned int r = u + 0x7FFF + ((u >> 16) & 1);
    return (unsigned short)(r >> 16);
}
__device__ __forceinline__ float sigm(float z) {
    return 1.0f / (1.0f + __expf(-z));
}
__device__ __forceinline__ void gload16(const unsigned short* g, unsigned short* l) {
    __builtin_amdgcn_global_load_lds(
        (const __attribute__((address_space(1))) void*)g,
        (__attribute__((address_space(3))) void*)l, 16, 0, 0);
}

// ============ Kernel 1: weight concat [384][2048] bf16 ============
__global__ __launch_bounds__(256)
void cvt_w(const float* __restrict__ Wq, const float* __restrict__ Wk,
           const float* __restrict__ Ww, unsigned short* __restrict__ Wc)
{
    const int r = blockIdx.x;
    const int c0 = threadIdx.x * 8;
    const float* src = nullptr;
    if (r < 256)      src = Wq + (size_t)r * HID;
    else if (r < 320) src = Wk + (size_t)(r - 256) * HID;
    else if (r < 324) src = Ww + (size_t)(r - 320) * HID;
    u16x8 o = {0, 0, 0, 0, 0, 0, 0, 0};
    if (src) {
        const float4 a = *(const float4*)(src + c0);
        const float4 b = *(const float4*)(src + c0 + 4);
        o[0] = f2bf(a.x); o[1] = f2bf(a.y); o[2] = f2bf(a.z); o[3] = f2bf(a.w);
        o[4] = f2bf(b.x); o[5] = f2bf(b.y); o[6] = f2bf(b.z); o[7] = f2bf(b.w);
    }
    *(u16x8*)(Wc + (size_t)r * HID + c0) = o;
}

// ============ Kernel 2: fused cvt_x + projection GEMM, 64x64 tiles ============
// (unchanged from r9 — proj is next round's target once score is fixed)
__global__ __launch_bounds__(256)
void proj_mfma(const float* __restrict__ x,
               const unsigned short* __restrict__ Wc,
               const float* __restrict__ bw,
               unsigned short* __restrict__ Qo,
               unsigned short* __restrict__ Ko,
               float* __restrict__ Wo)
{
    __shared__ unsigned short As[64 * 64];    // 8 KB
    __shared__ unsigned short Bs[64 * 64];    // 8 KB
    const int bid = blockIdx.x;
    const int w   = (bid & 7) * 96 + (bid >> 3);     // 768 = 8*96, bijective
    const int row0 = (w / 6) * 64;
    const int col0 = (w % 6) * 64;

    const int tid  = threadIdx.x;
    const int lane = tid & 63, wid = tid >> 6;
    const int wr = wid >> 1, wc = wid & 1;           // wave tile 32x32
    const int fr = lane & 15;

    const int ar = tid >> 2, ac2 = (tid & 3) * 2, asw = ar & 7;
    const float* Axg = x + (size_t)(row0 + ar) * HID + (tid & 3) * 16;

    const int sr = tid >> 3;
    const int scs = ((tid & 7) ^ (sr & 7)) * 8;
    const unsigned short* Bg = Wc + (size_t)(col0 + sr) * HID + scs;

    f32x4 acc[2][2];
    #pragma unroll
    for (int i = 0; i < 2; ++i)
        #pragma unroll
        for (int j = 0; j < 2; ++j) acc[i][j] = (f32x4){0.f, 0.f, 0.f, 0.f};

    for (int kt = 0; kt < HID; kt += 64) {
        const float4 a0 = *(const float4*)(Axg + kt);
        const float4 a1 = *(const float4*)(Axg + kt + 4);
        const float4 a2 = *(const float4*)(Axg + kt + 8);
        const float4 a3 = *(const float4*)(Axg + kt + 12);
        __syncthreads();
        #pragma unroll
        for (int c2 = 0; c2 < 2; ++c2)
            gload16(Bg + (size_t)c2 * 32 * HID + kt, &Bs[wid * 512 + c2 * 2048]);
        u16x8 c0v, c1v;
        c0v[0] = f2bf(a0.x); c0v[1] = f2bf(a0.y); c0v[2] = f2bf(a0.z); c0v[3] = f2bf(a0.w);
        c0v[4] = f2bf(a1.x); c0v[5] = f2bf(a1.y); c0v[6] = f2bf(a1.z); c0v[7] = f2bf(a1.w);
        c1v[0] = f2bf(a2.x); c1v[1] = f2bf(a2.y); c1v[2] = f2bf(a2.z); c1v[3] = f2bf(a2.w);
        c1v[4] = f2bf(a3.x); c1v[5] = f2bf(a3.y); c1v[6] = f2bf(a3.z); c1v[7] = f2bf(a3.w);
        *(u16x8*)&As[ar * 64 + ((ac2    ) ^ asw) * 8] = c0v;
        *(u16x8*)&As[ar * 64 + ((ac2 + 1) ^ asw) * 8] = c1v;
        __syncthreads();
        #pragma unroll
        for (int kk = 0; kk < 2; ++kk) {
            const int chnk = ((kk * 4 + (lane >> 4)) ^ (fr & 7)) * 8;
            bf16x8 af[2], bfv[2];
            #pragma unroll
            for (int mi = 0; mi < 2; ++mi)
                af[mi] = *(const bf16x8*)&As[(wr * 32 + mi * 16 + fr) * 64 + chnk];
            #pragma unroll
            for (int ni = 0; ni < 2; ++ni)
                bfv[ni] = *(const bf16x8*)&Bs[(wc * 32 + ni * 16 + fr) * 64 + chnk];
            #pragma unroll
            for (int mi = 0; mi < 2; ++mi)
                #pragma unroll
                for (int ni = 0; ni < 2; ++ni)
                    acc[mi][ni] = __builtin_amdgcn_mfma_f32_16x16x32_bf16(
                        af[mi], bfv[ni], acc[mi][ni], 0, 0, 0);
        }
    }

    const int orow = (lane >> 4) * 4, ocol = lane & 15;
    #pragma unroll
    for (int mi = 0; mi < 2; ++mi) {
        #pragma unroll
        for (int ni = 0; ni < 2; ++ni) {
            const int cg = col0 + wc * 32 + ni * 16 + ocol;
            #pragma unroll
            for (int j = 0; j < 4; ++j) {
                const int rg = row0 + wr * 32 + mi * 16 + orow + j;
                const float v = acc[mi][ni][j];
                if (cg < 256)       Qo[(size_t)rg * 256 + cg] = f2bf(sanef(v));
                else if (cg < 320)  Ko[(size_t)rg * 64 + (cg - 256)] = f2bf(sanef(v));
                else if (cg < 324)  Wo[(size_t)rg * 4 + (cg - 320)] = sanef(sigm(v + bw[cg - 320]));
            }
        }
    }
}

// ============ Kernel 3: merged scores, per-XCD balanced ============
// 3104 = 8*388 blocks. Each XCD: wx<264 -> compute (264 tiles), else fill
// (124 tiles) — fixes r8/r9's bug where XCDs 6-7 got ONLY fill and idled.
// Compute: mi-outer, stores spread over 4 phases, zero barriers/LDS.
__global__ __launch_bounds__(256, 4)
void score_all(const unsigned short* __restrict__ Qb,   // [8192][256]
               const unsigned short* __restrict__ Kb,   // [8192][64]
               const float* __restrict__ Wo,            // [8192][4] = sigmoid(w)
               const float* __restrict__ ib,
               float* __restrict__ out)
{
    const int bid = blockIdx.x;
    const int xcd = bid & 7, wx = bid >> 3;        // wx in [0,388)
    const int tid = threadIdx.x;

    if (wx >= 264) {                 // ---- fill: strict-upper 128x128 ----
        const int v = xcd * 124 + (wx - 264);      // [0,992)
        const int b = v / 496, u = v % 496;
        int p = (int)((sqrtf(8.f * u + 1.f) + 1.f) * 0.5f);
        while (p * (p - 1) / 2 > u) --p;
        while ((p + 1) * p / 2 <= u) ++p;
        const int q = u - p * (p - 1) / 2;
        const size_t obase = ((size_t)b * TSEQ + (size_t)q * 128) * TSEQ + (size_t)p * 128;
        const int row = tid >> 1, half = tid & 1;
        float4* po = (float4*)(out + obase + (size_t)row * TSEQ + half * 64);
        const float4 nh = make_float4(NEG_HUGE, NEG_HUGE, NEG_HUGE, NEG_HUGE);
        #pragma unroll
        for (int i = 0; i < 16; ++i) po[i] = nh;
        return;
    }

    // ---- compute: lower 128x64 tile ----
    const int w = xcd * 264 + wx;                  // [0,2112)
    const int b = w / 1056, u = w % 1056;
    int it = (int)((sqrtf(4.f * u + 1.f) - 1.f) * 0.5f);
    while (it * it + it > u) --it;
    while ((it + 1) * (it + 1) + (it + 1) <= u) ++it;
    const int jt = u - it * it - it;

    const int row0 = it * 128, col0 = jt * 64;
    const int brow = b * TSEQ + row0;
    const size_t obase = ((size_t)brow) * TSEQ + col0;
    const int lane = tid & 63, wid = tid >> 6;
    const int wr = wid >> 1, wc = wid & 1;
    const int fr = lane & 15, q4 = lane >> 4;

    const unsigned short* Qp = Qb + ((size_t)(brow + wr * 64 + fr)) * 256 + q4 * 8;
    const unsigned short* Kp = Kb + ((size_t)(b * TSEQ + col0 + wc * 32 + fr)) * 64 + q4 * 8;
    const f32x4 ibq = *(const f32x4*)ib;
    const float C1 = -SCALE * LOG2E;
    const bool diag = (col0 + 63 > row0);

    bf16x8 kf[2][2];                               // [kk][ni], reused all mi,h
    #pragma unroll
    for (int kk = 0; kk < 2; ++kk)
        #pragma unroll
        for (int ni = 0; ni < 2; ++ni)
            kf[kk][ni] = *(const bf16x8*)(Kp + (size_t)ni * 16 * 64 + kk * 32);

    #pragma unroll
    for (int mi = 0; mi < 4; ++mi) {
        const int r0 = wr * 64 + mi * 16 + q4 * 4;
        f32x4 wsv[4];                              // ws[row r0+j][4 heads]
        #pragma unroll
        for (int j = 0; j < 4; ++j)
            wsv[j] = *(const f32x4*)(Wo + (size_t)(brow + r0 + j) * 4);

        f32x4 fin0 = {0.f, 0.f, 0.f, 0.f}, fin1 = {0.f, 0.f, 0.f, 0.f};
        #pragma unroll
        for (int h = 0; h < 4; ++h) {
            const bf16x8 q0 = *(const bf16x8*)(Qp + (size_t)mi * 16 * 256 + h * 64);
            const bf16x8 q1 = *(const bf16x8*)(Qp + (size_t)mi * 16 * 256 + h * 64 + 32);
            f32x4 a0 = {0.f, 0.f, 0.f, 0.f}, a1 = {0.f, 0.f, 0.f, 0.f};
            a0 = __builtin_amdgcn_mfma_f32_16x16x32_bf16(q0, kf[0][0], a0, 0, 0, 0);
            a0 = __builtin_amdgcn_mfma_f32_16x16x32_bf16(q1, kf[1][0], a0, 0, 0, 0);
            a1 = __builtin_amdgcn_mfma_f32_16x16x32_bf16(q0, kf[0][1], a1, 0, 0, 0);
            a1 = __builtin_amdgcn_mfma_f32_16x16x32_bf16(q1, kf[1][1], a1, 0, 0, 0);
            // g = sigmoid(acc*SCALE+ib) = rcp(1+exp2(acc*C1+c0)); g,ws in [0,1]
            const float c0 = -ibq[h] * LOG2E;
            #pragma unroll
            for (int j = 0; j < 4; ++j) {
                const float wsj = wsv[j][h];
                fin0[j] += __builtin_amdgcn_rcpf(1.0f + EXP2(fmaf(a0[j], C1, c0))) * wsj;
                fin1[j] += __builtin_amdgcn_rcpf(1.0f + EXP2(fmaf(a1[j], C1, c0))) * wsj;
            }
        }

        #pragma unroll
        for (int j = 0; j < 4; ++j) {              // stores spread per-mi
            const int rl = r0 + j;
            const int cl0 = wc * 32 + fr, cl1 = cl0 + 16;
            float v0 = fin0[j], v1 = fin1[j];
            if (diag) {
                if (col0 + cl0 > row0 + rl) v0 = NEG_HUGE;
                if (col0 + cl1 > row0 + rl) v1 = NEG_HUGE;
            }
            out[obase + (size_t)rl * TSEQ + cl0] = v0;
            out[obase + (size_t)rl * TSEQ + cl1] = v1;
        }
    }
}

extern "C" void kernel_launch(void* const* d_in, const int* in_sizes, int n_in,
                              void* d_out, int out_size, void* d_ws, size_t ws_size,
                              hipStream_t stream)
{
    const float* x  = (const float*)d_in[0];
    const float* Wq = (const float*)d_in[1];
    const float* Wk = (const float*)d_in[2];
    const float* Ww = (const float*)d_in[3];
    const float* bw = (const float*)d_in[4];
    const float* ib = (const float*)d_in[5];
    float* out = (float*)d_out;

    unsigned short* Wc = (unsigned short*)d_ws;            // 1.5 MB
    unsigned short* Qo = Wc + (size_t)384 * HID;           // 4 MB
    unsigned short* Ko = Qo + (size_t)NROW * 256;          // 1 MB
    float*          Wo = (float*)(Ko + (size_t)NROW * 64); // 128 KB

    cvt_w<<<dim3(384), dim3(256), 0, stream>>>(Wq, Wk, Ww, Wc);
    proj_mfma<<<dim3(768), dim3(256), 0, stream>>>(x, Wc, bw, Qo, Ko, Wo);
    score_all<<<dim3(3104), dim3(256), 0, stream>>>(Qo, Ko, Wo, ib, out);
}

// Round 11
// 95.479 us; speedup vs baseline: 2.1327x; 1.0787x over previous
//
#include <hip/hip_runtime.h>
#include <cmath>

typedef __attribute__((ext_vector_type(4))) float f32x4;
typedef __attribute__((ext_vector_type(8))) short bf16x8;
typedef __attribute__((ext_vector_type(8))) unsigned short u16x8;

#define TSEQ 4096
#define NB 2
#define HID 2048
#define DD 64
#define NH 4
#define NROW 8192
#define SCALE 0.125f
#define NEG_HUGE -3.3e38f
#define LOG2E 1.4426950408889634f

#if __has_builtin(__builtin_amdgcn_exp2f)
#define EXP2(x) __builtin_amdgcn_exp2f(x)
#else
#define EXP2(x) exp2f(x)
#endif

__device__ __forceinline__ float sanef(float v) {
    return fminf(fmaxf(v, -3.3e38f), 3.3e38f);   // NaN->-3.3e38, +/-inf clamped
}
__device__ __forceinline__ unsigned short f2bf(float f) {  // RNE fp32->bf16
    unsigned int u = __float_as_uint(f);
    unsigned int r = u + 0x7FFF + ((u >> 16) & 1);
    return (unsigned short)(r >> 16);
}
__device__ __forceinline__ float sigm(float z) {
    return 1.0f / (1.0f + __expf(-z));
}
__device__ __forceinline__ void gload16(const unsigned short* g, unsigned short* l) {
    __builtin_amdgcn_global_load_lds(
        (const __attribute__((address_space(1))) void*)g,
        (__attribute__((address_space(3))) void*)l, 16, 0, 0);
}

// ============ Kernel 1: weight concat [384][2048] bf16 ============
__global__ __launch_bounds__(256)
void cvt_w(const float* __restrict__ Wq, const float* __restrict__ Wk,
           const float* __restrict__ Ww, unsigned short* __restrict__ Wc)
{
    const int r = blockIdx.x;
    const int c0 = threadIdx.x * 8;
    const float* src = nullptr;
    if (r < 256)      src = Wq + (size_t)r * HID;
    else if (r < 320) src = Wk + (size_t)(r - 256) * HID;
    else if (r < 324) src = Ww + (size_t)(r - 320) * HID;
    u16x8 o = {0, 0, 0, 0, 0, 0, 0, 0};
    if (src) {
        const float4 a = *(const float4*)(src + c0);
        const float4 b = *(const float4*)(src + c0 + 4);
        o[0] = f2bf(a.x); o[1] = f2bf(a.y); o[2] = f2bf(a.z); o[3] = f2bf(a.w);
        o[4] = f2bf(b.x); o[5] = f2bf(b.y); o[6] = f2bf(b.z); o[7] = f2bf(b.w);
    }
    *(u16x8*)(Wc + (size_t)r * HID + c0) = o;
}

// ============ Kernel 2: fused cvt_x + projection GEMM, 64x64 tiles ============
__global__ __launch_bounds__(256)
void proj_mfma(const float* __restrict__ x,
               const unsigned short* __restrict__ Wc,
               const float* __restrict__ bw,
               unsigned short* __restrict__ Qo,
               unsigned short* __restrict__ Ko,
               float* __restrict__ Wo)
{
    __shared__ unsigned short As[64 * 64];    // 8 KB
    __shared__ unsigned short Bs[64 * 64];    // 8 KB
    const int bid = blockIdx.x;
    const int w   = (bid & 7) * 96 + (bid >> 3);     // 768 = 8*96, bijective
    const int row0 = (w / 6) * 64;
    const int col0 = (w % 6) * 64;

    const int tid  = threadIdx.x;
    const int lane = tid & 63, wid = tid >> 6;
    const int wr = wid >> 1, wc = wid & 1;           // wave tile 32x32
    const int fr = lane & 15;

    const int ar = tid >> 2, ac2 = (tid & 3) * 2, asw = ar & 7;
    const float* Axg = x + (size_t)(row0 + ar) * HID + (tid & 3) * 16;

    const int sr = tid >> 3;
    const int scs = ((tid & 7) ^ (sr & 7)) * 8;
    const unsigned short* Bg = Wc + (size_t)(col0 + sr) * HID + scs;

    f32x4 acc[2][2];
    #pragma unroll
    for (int i = 0; i < 2; ++i)
        #pragma unroll
        for (int j = 0; j < 2; ++j) acc[i][j] = (f32x4){0.f, 0.f, 0.f, 0.f};

    for (int kt = 0; kt < HID; kt += 64) {
        const float4 a0 = *(const float4*)(Axg + kt);
        const float4 a1 = *(const float4*)(Axg + kt + 4);
        const float4 a2 = *(const float4*)(Axg + kt + 8);
        const float4 a3 = *(const float4*)(Axg + kt + 12);
        __syncthreads();
        #pragma unroll
        for (int c2 = 0; c2 < 2; ++c2)
            gload16(Bg + (size_t)c2 * 32 * HID + kt, &Bs[wid * 512 + c2 * 2048]);
        u16x8 c0v, c1v;
        c0v[0] = f2bf(a0.x); c0v[1] = f2bf(a0.y); c0v[2] = f2bf(a0.z); c0v[3] = f2bf(a0.w);
        c0v[4] = f2bf(a1.x); c0v[5] = f2bf(a1.y); c0v[6] = f2bf(a1.z); c0v[7] = f2bf(a1.w);
        c1v[0] = f2bf(a2.x); c1v[1] = f2bf(a2.y); c1v[2] = f2bf(a2.z); c1v[3] = f2bf(a2.w);
        c1v[4] = f2bf(a3.x); c1v[5] = f2bf(a3.y); c1v[6] = f2bf(a3.z); c1v[7] = f2bf(a3.w);
        *(u16x8*)&As[ar * 64 + ((ac2    ) ^ asw) * 8] = c0v;
        *(u16x8*)&As[ar * 64 + ((ac2 + 1) ^ asw) * 8] = c1v;
        __syncthreads();
        #pragma unroll
        for (int kk = 0; kk < 2; ++kk) {
            const int chnk = ((kk * 4 + (lane >> 4)) ^ (fr & 7)) * 8;
            bf16x8 af[2], bfv[2];
            #pragma unroll
            for (int mi = 0; mi < 2; ++mi)
                af[mi] = *(const bf16x8*)&As[(wr * 32 + mi * 16 + fr) * 64 + chnk];
            #pragma unroll
            for (int ni = 0; ni < 2; ++ni)
                bfv[ni] = *(const bf16x8*)&Bs[(wc * 32 + ni * 16 + fr) * 64 + chnk];
            #pragma unroll
            for (int mi = 0; mi < 2; ++mi)
                #pragma unroll
                for (int ni = 0; ni < 2; ++ni)
                    acc[mi][ni] = __builtin_amdgcn_mfma_f32_16x16x32_bf16(
                        af[mi], bfv[ni], acc[mi][ni], 0, 0, 0);
        }
    }

    const int orow = (lane >> 4) * 4, ocol = lane & 15;
    #pragma unroll
    for (int mi = 0; mi < 2; ++mi) {
        #pragma unroll
        for (int ni = 0; ni < 2; ++ni) {
            const int cg = col0 + wc * 32 + ni * 16 + ocol;
            #pragma unroll
            for (int j = 0; j < 4; ++j) {
                const int rg = row0 + wr * 32 + mi * 16 + orow + j;
                const float v = acc[mi][ni][j];
                if (cg < 256)       Qo[(size_t)rg * 256 + cg] = f2bf(sanef(v));
                else if (cg < 320)  Ko[(size_t)rg * 64 + (cg - 256)] = f2bf(sanef(v));
                else if (cg < 324)  Wo[(size_t)rg * 4 + (cg - 320)] = sanef(sigm(v + bw[cg - 320]));
            }
        }
    }
}

// ============ Kernel 3: merged scores, 1-wave blocks, 8 waves/SIMD target ============
// 9440 = 8*1180 blocks of 64 threads. Per XCD: 1056 compute quarter-tiles
// (64x32 out each) + 124 fill tiles (128x128). Zero LDS/barriers; VGPR <= 64
// (launch_bounds(64,8)) doubles resident waves vs r10's 84-VGPR 4/SIMD bin.
__global__ __launch_bounds__(64, 8)
void score_all(const unsigned short* __restrict__ Qb,   // [8192][256]
               const unsigned short* __restrict__ Kb,   // [8192][64]
               const float* __restrict__ Wo,            // [8192][4] = sigmoid(w)
               const float* __restrict__ ib,
               float* __restrict__ out)
{
    const int bid = blockIdx.x;
    const int xcd = bid & 7, wx = bid >> 3;        // wx in [0,1180)
    const int lane = threadIdx.x;

    if (wx >= 1056) {                // ---- fill: strict-upper 128x128 ----
        const int v = xcd * 124 + (wx - 1056);     // [0,992)
        const int b = v / 496, u = v % 496;
        int p = (int)((sqrtf(8.f * u + 1.f) + 1.f) * 0.5f);
        while (p * (p - 1) / 2 > u) --p;
        while ((p + 1) * p / 2 <= u) ++p;
        const int q = u - p * (p - 1) / 2;
        const size_t obase = ((size_t)b * TSEQ + (size_t)q * 128) * TSEQ + (size_t)p * 128;
        // lanes 0-31 -> row 2i cols, lanes 32-63 -> row 2i+1 (coalesced 1KB/row)
        float4* po = (float4*)(out + obase + (size_t)(lane >> 5) * TSEQ) + (lane & 31);
        const float4 nh = make_float4(NEG_HUGE, NEG_HUGE, NEG_HUGE, NEG_HUGE);
        #pragma unroll 8
        for (int i = 0; i < 64; ++i) {
            *po = nh;
            po += 2 * TSEQ / 4;
        }
        return;
    }

    // ---- compute: quarter (64x32) of a lower 128x64 tile ----
    const int v = xcd * 1056 + wx;                 // [0,8448)
    const int tile = v >> 2, s = v & 3;
    const int wr = s >> 1, wc = s & 1;
    const int b = tile / 1056, u = tile % 1056;
    int it = (int)((sqrtf(4.f * u + 1.f) - 1.f) * 0.5f);
    while (it * it + it > u) --it;
    while ((it + 1) * (it + 1) + (it + 1) <= u) ++it;
    const int jt = u - it * it - it;

    const int row0 = it * 128, col0 = jt * 64;
    const int brow = b * TSEQ + row0;
    const int fr = lane & 15, q4 = lane >> 4;

    const unsigned short* Qp = Qb + ((size_t)(brow + wr * 64 + fr)) * 256 + q4 * 8;
    const unsigned short* Kp = Kb + ((size_t)(b * TSEQ + col0 + wc * 32 + fr)) * 64 + q4 * 8;
    const float* Wop = Wo + (size_t)(brow + wr * 64 + q4 * 4) * 4;   // +[(mi*16+j)*4+h]
    const float C1 = -SCALE * LOG2E;
    const bool diag = (col0 + 63 > row0);

    bf16x8 kf[2][2];                               // [kk][ni], reused all mi,h
    #pragma unroll
    for (int kk = 0; kk < 2; ++kk)
        #pragma unroll
        for (int ni = 0; ni < 2; ++ni)
            kf[kk][ni] = *(const bf16x8*)(Kp + (size_t)ni * 16 * 64 + kk * 32);

    #pragma unroll
    for (int mi = 0; mi < 4; ++mi) {
        const int r0 = wr * 64 + mi * 16 + q4 * 4;
        f32x4 fin0 = {0.f, 0.f, 0.f, 0.f}, fin1 = {0.f, 0.f, 0.f, 0.f};
        #pragma unroll
        for (int h = 0; h < 4; ++h) {
            const bf16x8 q0 = *(const bf16x8*)(Qp + (size_t)mi * 16 * 256 + h * 64);
            const bf16x8 q1 = *(const bf16x8*)(Qp + (size_t)mi * 16 * 256 + h * 64 + 32);
            f32x4 a0 = {0.f, 0.f, 0.f, 0.f}, a1 = {0.f, 0.f, 0.f, 0.f};
            a0 = __builtin_amdgcn_mfma_f32_16x16x32_bf16(q0, kf[0][0], a0, 0, 0, 0);
            a0 = __builtin_amdgcn_mfma_f32_16x16x32_bf16(q1, kf[1][0], a0, 0, 0, 0);
            a1 = __builtin_amdgcn_mfma_f32_16x16x32_bf16(q0, kf[0][1], a1, 0, 0, 0);
            a1 = __builtin_amdgcn_mfma_f32_16x16x32_bf16(q1, kf[1][1], a1, 0, 0, 0);
            // ib[h] is wave-uniform -> SGPR; Wop loads use immediate offsets.
            const float c0 = -ib[h] * LOG2E;
            #pragma unroll
            for (int j = 0; j < 4; ++j) {
                const float wsj = Wop[(mi * 16 + j) * 4 + h];
                fin0[j] += __builtin_amdgcn_rcpf(1.0f + EXP2(fmaf(a0[j], C1, c0))) * wsj;
                fin1[j] += __builtin_amdgcn_rcpf(1.0f + EXP2(fmaf(a1[j], C1, c0))) * wsj;
            }
        }

        const size_t obase = ((size_t)brow) * TSEQ + col0;
        #pragma unroll
        for (int j = 0; j < 4; ++j) {
            const int rl = r0 + j;
            const int cl0 = wc * 32 + fr, cl1 = cl0 + 16;
            float v0 = fin0[j], v1 = fin1[j];
            if (diag) {
                if (col0 + cl0 > row0 + rl) v0 = NEG_HUGE;
                if (col0 + cl1 > row0 + rl) v1 = NEG_HUGE;
            }
            out[obase + (size_t)rl * TSEQ + cl0] = v0;
            out[obase + (size_t)rl * TSEQ + cl1] = v1;
        }
    }
}

extern "C" void kernel_launch(void* const* d_in, const int* in_sizes, int n_in,
                              void* d_out, int out_size, void* d_ws, size_t ws_size,
                              hipStream_t stream)
{
    const float* x  = (const float*)d_in[0];
    const float* Wq = (const float*)d_in[1];
    const float* Wk = (const float*)d_in[2];
    const float* Ww = (const float*)d_in[3];
    const float* bw = (const float*)d_in[4];
    const float* ib = (const float*)d_in[5];
    float* out = (float*)d_out;

    unsigned short* Wc = (unsigned short*)d_ws;            // 1.5 MB
    unsigned short* Qo = Wc + (size_t)384 * HID;           // 4 MB
    unsigned short* Ko = Qo + (size_t)NROW * 256;          // 1 MB
    float*          Wo = (float*)(Ko + (size_t)NROW * 64); // 128 KB

    cvt_w<<<dim3(384), dim3(256), 0, stream>>>(Wq, Wk, Ww, Wc);
    proj_mfma<<<dim3(768), dim3(256), 0, stream>>>(x, Wc, bw, Qo, Ko, Wo);
    score_all<<<dim3(9440), dim3(64), 0, stream>>>(Qo, Ko, Wo, ib, out);
}